// Round 8
// baseline (291.738 us; speedup 1.0000x reference)
//
#include <hip/hip_runtime.h>
#include <hip/hip_bf16.h>

#define HID 128
#define MAXD 64  // per-node fast-path degree cap (Poisson(6) max ~25)

typedef __attribute__((ext_vector_type(8))) short bfrag8;
typedef __attribute__((ext_vector_type(4))) short bf4;
typedef __attribute__((ext_vector_type(4))) float facc4;

// f32 -> bf16 bits, round-to-nearest-even
__device__ inline short f2bf(float x) {
  unsigned u = __builtin_bit_cast(unsigned, x);
  u += 0x7fffu + ((u >> 16) & 1u);
  return (short)(u >> 16);
}
__device__ inline float bf2f(short s) {
  unsigned u = ((unsigned)(unsigned short)s) << 16;
  return __builtin_bit_cast(float, u);
}

__device__ inline void store_val(float* Y, size_t i, float v) { Y[i] = v; }
__device__ inline void store_val(short* Y, size_t i, float v) { Y[i] = f2bf(v); }

// ---------------------------------------------------------------------------
// One-shot weight pre-format: f32 W -> fragment-linear bf16 chunks.
// Chunks 0..8191: Wq,Wk,Wv,Wout (2048 each), layout ct<<8|kt<<6|g<<4|c.
// Chunks 8192..9215: [Wtq|Wtk] (1024), layout qk<<9|ct<<6|g<<4|c.
// ---------------------------------------------------------------------------
__global__ __launch_bounds__(256) void preformat_k(
    const float* __restrict__ Wq, const float* __restrict__ Wk,
    const float* __restrict__ Wv, const float* __restrict__ Wout,
    const float* __restrict__ Wtq, const float* __restrict__ Wtk,
    short* __restrict__ out) {
  int gid = blockIdx.x * 256 + threadIdx.x;
  if (gid >= 9216) return;
  bfrag8 v;
  if (gid < 8192) {
    int which = gid >> 11;
    int chunk = gid & 2047;
    const float* W = (which == 0) ? Wq : (which == 1) ? Wk
                   : (which == 2) ? Wv : Wout;
    int c  = chunk & 15;
    int g  = (chunk >> 4) & 3;
    int kt = (chunk >> 6) & 3;
    int ct = chunk >> 8;
    int col = ct * 16 + c;
    int k0 = kt * 32 + g * 8;
    #pragma unroll
    for (int i = 0; i < 8; ++i) v[i] = f2bf(W[(size_t)(k0 + i) * HID + col]);
  } else {
    int chunk = gid - 8192;
    int c  = chunk & 15;
    int g  = (chunk >> 4) & 3;
    int ct = (chunk >> 6) & 7;
    int qk = chunk >> 9;
    const float* W = qk ? Wtk : Wtq;
    int col = ct * 16 + c;
    int k0 = g * 8;
    #pragma unroll
    for (int i = 0; i < 8; ++i) v[i] = f2bf(W[(size_t)(k0 + i) * HID + col]);
  }
  *(bfrag8*)(out + (size_t)gid * 8) = v;
}

// ---------------------------------------------------------------------------
// Y = X @ W + b via bf16 MFMA (single-MFMA, inputs rounded to bf16 — the
// result is stored bf16 anyway, so split-X precision would be discarded).
// MODE 0: Y[row*128+col] (OT float or short)
// MODE 1: Q-pack into QV[row*256 + (col>>2)*8 + (col&3)]
// MODE 2: V-pack into QV[row*256 + (col>>2)*8 + (col&3) + 4]
// ---------------------------------------------------------------------------
template <typename IT, typename OT, int MODE>
__global__ __launch_bounds__(256) void gemm_mfma_k(
    const IT* __restrict__ X, const short* __restrict__ Wp,
    const float* __restrict__ b, OT* __restrict__ Y, int nrows) {
  __shared__ short Ws[8 * 4 * 4 * 16 * 8];  // 32KB
  const int t = threadIdx.x;

  #pragma unroll
  for (int it = 0; it < 8; ++it) {
    int chunk = t + it * 256;
    *(bfrag8*)(&Ws[chunk * 8]) = *(const bfrag8*)(Wp + (size_t)chunk * 8);
  }
  __syncthreads();

  const int w  = t >> 6;
  const int l  = t & 63;
  const int lr = l & 15;
  const int g  = l >> 4;
  const int row0 = blockIdx.x * 64 + w * 16;
  const int arow = min(row0 + lr, nrows - 1);

  facc4 acc[8];
  #pragma unroll
  for (int i = 0; i < 8; ++i) acc[i] = (facc4){0.f, 0.f, 0.f, 0.f};

  #pragma unroll
  for (int kt = 0; kt < 4; ++kt) {
    bfrag8 a;
    if constexpr (sizeof(IT) == 4) {
      const float* xp = (const float*)X + (size_t)arow * HID + kt * 32 + g * 8;
      float xv[8];
      *(facc4*)(xv)     = *(const facc4*)(xp);
      *(facc4*)(xv + 4) = *(const facc4*)(xp + 4);
      #pragma unroll
      for (int i = 0; i < 8; ++i) a[i] = f2bf(xv[i]);
    } else {
      a = *(const bfrag8*)((const short*)X + (size_t)arow * HID + kt * 32 + g * 8);
    }
    #pragma unroll
    for (int ct = 0; ct < 8; ++ct) {
      bfrag8 bf = *(const bfrag8*)(&Ws[(((ct * 4 + kt) * 4 + g) * 16 + lr) * 8]);
      acc[ct] = __builtin_amdgcn_mfma_f32_16x16x32_bf16(a, bf, acc[ct], 0, 0, 0);
    }
  }

  #pragma unroll
  for (int ct = 0; ct < 8; ++ct) {
    int col = ct * 16 + lr;
    float bias = b[col];
    #pragma unroll
    for (int r = 0; r < 4; ++r) {
      int row = row0 + g * 4 + r;
      if (row < nrows) {
        size_t oidx;
        if constexpr (MODE == 0) oidx = (size_t)row * HID + col;
        else oidx = (size_t)row * 256 + ((col >> 2) << 3) + (col & 3) +
                    (MODE == 2 ? 4 : 0);
        store_val(Y, oidx, acc[ct][r] + bias);
      }
    }
  }
}

// ---------------------------------------------------------------------------
// Temporal scores via MFMA, edges-on-COLUMNS mapping (A = W fragment,
// B = T^T fragment). Single-MFMA (bf16 T; added score error ~0.01 on sigma~4.5
// scores — negligible). Lane holds 4 features of one edge; head-dot = 4
// in-lane FMAs + 2 shuffles.
// ---------------------------------------------------------------------------
__global__ __launch_bounds__(256, 8) void temporal_mfma_k(
    const float* __restrict__ T, const short* __restrict__ Wp,
    const float* __restrict__ btq, const float* __restrict__ btk,
    float* __restrict__ ts, int E, int ntiles) {
  __shared__ short Ws[2 * 8 * 4 * 16 * 8];  // 16KB
  __shared__ float bsh[256];                // [0..127]=btq, [128..255]=btk
  const int t = threadIdx.x;

  #pragma unroll
  for (int it = 0; it < 4; ++it) {
    int chunk = t + it * 256;
    *(bfrag8*)(&Ws[chunk * 8]) = *(const bfrag8*)(Wp + (size_t)chunk * 8);
  }
  bsh[t] = (t < 128) ? btq[t] : btk[t - 128];
  __syncthreads();

  const int w = t >> 6;
  const int l = t & 63;
  const int c = l & 15;  // edge within 16-edge wave tile (MFMA column)
  const int g = l >> 4;  // feature-row group

  for (int tile = blockIdx.x; tile < ntiles; tile += gridDim.x) {
    const int e0 = tile * 64 + w * 16;
    const int ar = min(e0 + c, E - 1);
    const float* tp = T + (size_t)ar * 32 + g * 8;
    float xv[8];
    *(facc4*)(xv)     = *(const facc4*)(tp);
    *(facc4*)(xv + 4) = *(const facc4*)(tp + 4);
    bfrag8 tb;
    #pragma unroll
    for (int i = 0; i < 8; ++i) tb[i] = f2bf(xv[i]);
    const bool full = (e0 + 15 < E);

    #pragma unroll 1
    for (int ct = 0; ct < 8; ++ct) {
      facc4 accq = *(const facc4*)(&bsh[ct * 16 + g * 4]);
      bfrag8 wq = *(const bfrag8*)(&Ws[(ct * 64 + g * 16 + c) * 8]);
      accq = __builtin_amdgcn_mfma_f32_16x16x32_bf16(wq, tb, accq, 0, 0, 0);
      facc4 acck = *(const facc4*)(&bsh[128 + ct * 16 + g * 4]);
      bfrag8 wk = *(const bfrag8*)(&Ws[(512 + ct * 64 + g * 16 + c) * 8]);
      acck = __builtin_amdgcn_mfma_f32_16x16x32_bf16(wk, tb, acck, 0, 0, 0);

      float s = accq[0] * acck[0] + accq[1] * acck[1] +
                accq[2] * acck[2] + accq[3] * acck[3];
      s += __shfl_xor(s, 16, 64);
      s += __shfl_xor(s, 32, 64);
      if (g == (ct & 3)) {
        int e = e0 + c;
        if (full || e < E) ts[(size_t)e * 8 + ct] = s;
      }
    }
  }
}

// ---------------------------------------------------------------------------
// CSR build
// ---------------------------------------------------------------------------
__global__ __launch_bounds__(256) void count_deg_k(const int* __restrict__ tgt,
                                                   int* __restrict__ deg, int E) {
  int gid = blockIdx.x * 256 + threadIdx.x;
  if (gid < E) atomicAdd(&deg[tgt[gid]], 1);
}

__global__ __launch_bounds__(256) void block_sum_k(const int* __restrict__ deg,
                                                   int* __restrict__ bsum, int n) {
  __shared__ int sd[256];
  const int base = blockIdx.x * 1024;
  const int t = threadIdx.x;
  int s = 0;
  #pragma unroll
  for (int j = 0; j < 4; ++j) {
    int i = base + t + j * 256;
    if (i < n) s += deg[i];
  }
  sd[t] = s;
  __syncthreads();
  for (int st = 128; st; st >>= 1) {
    if (t < st) sd[t] += sd[t + st];
    __syncthreads();
  }
  if (t == 0) bsum[blockIdx.x] = sd[0];
}

__global__ __launch_bounds__(1024) void scan_partials_k(const int* __restrict__ bsum,
                                                        int* __restrict__ boff, int G) {
  __shared__ int sd[1024];
  const int t = threadIdx.x;
  int v = (t < G) ? bsum[t] : 0;
  sd[t] = v;
  __syncthreads();
  for (int s = 1; s < 1024; s <<= 1) {
    int a = (t >= s) ? sd[t - s] : 0;
    __syncthreads();
    sd[t] += a;
    __syncthreads();
  }
  if (t < G) boff[t] = sd[t] - v;
}

__global__ __launch_bounds__(256) void block_scan_k(const int* __restrict__ deg,
                                                    const int* __restrict__ boff,
                                                    int* __restrict__ off, int n) {
  __shared__ int sd[256];
  const int base = blockIdx.x * 1024;
  const int t = threadIdx.x;
  const int i0 = base + t * 4;
  int v[4];
  int s = 0;
  #pragma unroll
  for (int j = 0; j < 4; ++j) {
    v[j] = (i0 + j < n) ? deg[i0 + j] : 0;
    s += v[j];
  }
  const int own = s;
  sd[t] = s;
  __syncthreads();
  for (int st = 1; st < 256; st <<= 1) {
    int a = (t >= st) ? sd[t - st] : 0;
    __syncthreads();
    sd[t] += a;
    __syncthreads();
  }
  int acc = boff[blockIdx.x] + sd[t] - own;
  #pragma unroll
  for (int j = 0; j < 4; ++j) {
    int idx = i0 + j;
    if (idx < n) {
      off[idx] = acc;
      acc += v[j];
      if (idx == n - 1) off[n] = acc;
    }
  }
}

// writes (edge id, src id) pairs so the softmax kernel never gathers src[]
__global__ __launch_bounds__(256) void scatter_k(const int* __restrict__ src,
                                                 const int* __restrict__ tgt,
                                                 const int* __restrict__ off,
                                                 int* __restrict__ cur,
                                                 int2* __restrict__ elist2, int E) {
  int gid = blockIdx.x * 256 + threadIdx.x;
  if (gid < E) {
    int n = tgt[gid];
    int p = atomicAdd(&cur[n], 1);
    elist2[off[n] + p] = make_int2(gid, src[gid]);
  }
}

// ---------------------------------------------------------------------------
// Per-node QK score + softmax + aggregation, ONE gather pass, no max-tracking
// (scores bounded ~|30| << 88 so fp32 exp is safe; softmax is shift-invariant).
// QV packed rows: lane g reads 16B = {Q feats g*4..+3, V feats g*4..+3}.
// 32 lanes per node, 8 nodes per 256-thread block, no __syncthreads.
// ---------------------------------------------------------------------------
__global__ __launch_bounds__(256) void softmax_agg_k(
    const float* __restrict__ tscores, const short* __restrict__ QVp,
    const short* __restrict__ Kp, const int* __restrict__ off,
    const int2* __restrict__ elist2, float* __restrict__ attn_w,
    short* __restrict__ aggb, int N) {
  __shared__ int esh[8][MAXD];
  __shared__ int ssh[8][MAXD];
  __shared__ float sraw[8][MAXD][8];  // unnormalized exp weights per head
  const int t = threadIdx.x;
  const int grp = t >> 5;
  const int g = t & 31;
  const int h = g >> 2;
  const int j = g & 3;
  const int n = blockIdx.x * 8 + grp;
  if (n >= N) return;

  const int s0 = off[n];
  const int deg = off[n + 1] - s0;

  float kr[4];
  {
    bf4 k4 = *(const bf4*)(Kp + (size_t)n * HID + g * 4);
    #pragma unroll
    for (int q = 0; q < 4; ++q) kr[q] = bf2f(k4[q]);
  }

  if (deg <= MAXD) {
    for (int i = g; i < deg; i += 32) {
      int2 es = elist2[s0 + i];
      esh[grp][i] = es.x;
      ssh[grp][i] = es.y;
    }

    float lsum = 0.f;
    float a0 = 0.f, a1 = 0.f, a2 = 0.f, a3 = 0.f;
    int i = 0;
    for (; i + 4 <= deg; i += 4) {
      bfrag8 qv0 = *(const bfrag8*)(QVp + (size_t)ssh[grp][i]     * 256 + g * 8);
      bfrag8 qv1 = *(const bfrag8*)(QVp + (size_t)ssh[grp][i + 1] * 256 + g * 8);
      bfrag8 qv2 = *(const bfrag8*)(QVp + (size_t)ssh[grp][i + 2] * 256 + g * 8);
      bfrag8 qv3 = *(const bfrag8*)(QVp + (size_t)ssh[grp][i + 3] * 256 + g * 8);
      float ts0 = tscores[(size_t)esh[grp][i]     * 8 + h];
      float ts1 = tscores[(size_t)esh[grp][i + 1] * 8 + h];
      float ts2 = tscores[(size_t)esh[grp][i + 2] * 8 + h];
      float ts3 = tscores[(size_t)esh[grp][i + 3] * 8 + h];
      float p0 = bf2f(qv0[0]) * kr[0] + bf2f(qv0[1]) * kr[1] +
                 bf2f(qv0[2]) * kr[2] + bf2f(qv0[3]) * kr[3];
      float p1 = bf2f(qv1[0]) * kr[0] + bf2f(qv1[1]) * kr[1] +
                 bf2f(qv1[2]) * kr[2] + bf2f(qv1[3]) * kr[3];
      float p2 = bf2f(qv2[0]) * kr[0] + bf2f(qv2[1]) * kr[1] +
                 bf2f(qv2[2]) * kr[2] + bf2f(qv2[3]) * kr[3];
      float p3 = bf2f(qv3[0]) * kr[0] + bf2f(qv3[1]) * kr[1] +
                 bf2f(qv3[2]) * kr[2] + bf2f(qv3[3]) * kr[3];
      p0 += __shfl_xor(p0, 1, 4); p0 += __shfl_xor(p0, 2, 4);
      p1 += __shfl_xor(p1, 1, 4); p1 += __shfl_xor(p1, 2, 4);
      p2 += __shfl_xor(p2, 1, 4); p2 += __shfl_xor(p2, 2, 4);
      p3 += __shfl_xor(p3, 1, 4); p3 += __shfl_xor(p3, 2, 4);
      float w0 = __expf(ts0 + p0 * 0.25f);
      float w1 = __expf(ts1 + p1 * 0.25f);
      float w2 = __expf(ts2 + p2 * 0.25f);
      float w3 = __expf(ts3 + p3 * 0.25f);
      if (j == 0) {
        sraw[grp][i][h]     = w0;
        sraw[grp][i + 1][h] = w1;
        sraw[grp][i + 2][h] = w2;
        sraw[grp][i + 3][h] = w3;
      }
      lsum += (w0 + w1) + (w2 + w3);
      a0 += w0 * bf2f(qv0[4]) + w1 * bf2f(qv1[4]) +
            w2 * bf2f(qv2[4]) + w3 * bf2f(qv3[4]);
      a1 += w0 * bf2f(qv0[5]) + w1 * bf2f(qv1[5]) +
            w2 * bf2f(qv2[5]) + w3 * bf2f(qv3[5]);
      a2 += w0 * bf2f(qv0[6]) + w1 * bf2f(qv1[6]) +
            w2 * bf2f(qv2[6]) + w3 * bf2f(qv3[6]);
      a3 += w0 * bf2f(qv0[7]) + w1 * bf2f(qv1[7]) +
            w2 * bf2f(qv2[7]) + w3 * bf2f(qv3[7]);
    }
    for (; i < deg; ++i) {
      bfrag8 qv0 = *(const bfrag8*)(QVp + (size_t)ssh[grp][i] * 256 + g * 8);
      float ts0 = tscores[(size_t)esh[grp][i] * 8 + h];
      float p0 = bf2f(qv0[0]) * kr[0] + bf2f(qv0[1]) * kr[1] +
                 bf2f(qv0[2]) * kr[2] + bf2f(qv0[3]) * kr[3];
      p0 += __shfl_xor(p0, 1, 4); p0 += __shfl_xor(p0, 2, 4);
      float w0 = __expf(ts0 + p0 * 0.25f);
      if (j == 0) sraw[grp][i][h] = w0;
      lsum += w0;
      a0 += w0 * bf2f(qv0[4]);
      a1 += w0 * bf2f(qv0[5]);
      a2 += w0 * bf2f(qv0[6]);
      a3 += w0 * bf2f(qv0[7]);
    }
    float invl = (lsum > 0.f) ? 1.0f / lsum : 0.f;

    bf4 st;
    st[0] = f2bf(a0 * invl); st[1] = f2bf(a1 * invl);
    st[2] = f2bf(a2 * invl); st[3] = f2bf(a3 * invl);
    *(bf4*)(aggb + (size_t)n * HID + g * 4) = st;

    if (j == 0) {
      for (int q = 0; q < deg; ++q)
        attn_w[(size_t)esh[grp][q] * 8 + h] = sraw[grp][q][h] * invl;
    }
  } else {
    // fallback (deg > MAXD): 3-pass unstaged, max-subtracted
    float m = -3.0e38f;
    for (int q = 0; q < deg; ++q) {
      int2 es = elist2[s0 + q];
      bfrag8 q4 = *(const bfrag8*)(QVp + (size_t)es.y * 256 + g * 8);
      float p = bf2f(q4[0]) * kr[0] + bf2f(q4[1]) * kr[1] +
                bf2f(q4[2]) * kr[2] + bf2f(q4[3]) * kr[3];
      p += __shfl_xor(p, 1, 4); p += __shfl_xor(p, 2, 4);
      m = fmaxf(m, tscores[(size_t)es.x * 8 + h] + p * 0.25f);
    }
    float l = 0.f;
    for (int q = 0; q < deg; ++q) {
      int2 es = elist2[s0 + q];
      bfrag8 q4 = *(const bfrag8*)(QVp + (size_t)es.y * 256 + g * 8);
      float p = bf2f(q4[0]) * kr[0] + bf2f(q4[1]) * kr[1] +
                bf2f(q4[2]) * kr[2] + bf2f(q4[3]) * kr[3];
      p += __shfl_xor(p, 1, 4); p += __shfl_xor(p, 2, 4);
      l += __expf(tscores[(size_t)es.x * 8 + h] + p * 0.25f - m);
    }
    float invl = (l > 0.f) ? 1.0f / l : 0.f;
    float a0 = 0.f, a1 = 0.f, a2 = 0.f, a3 = 0.f;
    for (int q = 0; q < deg; ++q) {
      int2 es = elist2[s0 + q];
      bfrag8 q4 = *(const bfrag8*)(QVp + (size_t)es.y * 256 + g * 8);
      float p = bf2f(q4[0]) * kr[0] + bf2f(q4[1]) * kr[1] +
                bf2f(q4[2]) * kr[2] + bf2f(q4[3]) * kr[3];
      p += __shfl_xor(p, 1, 4); p += __shfl_xor(p, 2, 4);
      float w = __expf(tscores[(size_t)es.x * 8 + h] + p * 0.25f - m) * invl;
      a0 += w * bf2f(q4[4]);
      a1 += w * bf2f(q4[5]);
      a2 += w * bf2f(q4[6]);
      a3 += w * bf2f(q4[7]);
      if (j == 0) attn_w[(size_t)es.x * 8 + h] = w;
    }
    bf4 st;
    st[0] = f2bf(a0); st[1] = f2bf(a1); st[2] = f2bf(a2); st[3] = f2bf(a3);
    *(bf4*)(aggb + (size_t)n * HID + g * 4) = st;
  }
}

// ---------------------------------------------------------------------------
extern "C" void kernel_launch(void* const* d_in, const int* in_sizes, int n_in,
                              void* d_out, int out_size, void* d_ws, size_t ws_size,
                              hipStream_t stream) {
  const float* query    = (const float*)d_in[0];
  const float* key      = (const float*)d_in[1];
  const float* value    = (const float*)d_in[2];
  const float* temporal = (const float*)d_in[3];
  const int*   eidx     = (const int*)d_in[4];
  const float* Wq   = (const float*)d_in[5];
  const float* bq   = (const float*)d_in[6];
  const float* Wk   = (const float*)d_in[7];
  const float* bk   = (const float*)d_in[8];
  const float* Wv   = (const float*)d_in[9];
  const float* bv   = (const float*)d_in[10];
  const float* Wtq  = (const float*)d_in[11];
  const float* btq  = (const float*)d_in[12];
  const float* Wtk  = (const float*)d_in[13];
  const float* btk  = (const float*)d_in[14];
  const float* Wout = (const float*)d_in[15];
  const float* bout = (const float*)d_in[16];

  const int N = in_sizes[0] / HID;
  const int E = in_sizes[4] / 2;
  const int* src = eidx;
  const int* tgt = eidx + E;

  char* ws = (char*)d_ws;
  short* QVp = (short*)ws;                     ws += (size_t)N * 256 * 2;
  short* Kp = (short*)ws;                      ws += (size_t)N * HID * 2;
  short* aggb = (short*)ws;                    ws += (size_t)N * HID * 2;
  float* tscores = (float*)ws;                 ws += (size_t)E * 8 * 4;
  int* deg   = (int*)ws;                       ws += (size_t)N * 4;
  int* cur   = (int*)ws;                       ws += (size_t)N * 4;
  int* off   = (int*)ws;                       ws += (size_t)(N + 2) * 4;  // pad->8B align
  int2* elist2 = (int2*)ws;                    ws += (size_t)E * 8;
  int* bsum  = (int*)ws;                       ws += 1024 * 4;
  int* boff  = (int*)ws;                       ws += 1024 * 4;
  short* Wpre = (short*)ws;                    // 9216 * 16B

  const int G = (N + 1023) / 1024;

  hipMemsetAsync(deg, 0, sizeof(int) * 2 * (size_t)N, stream);  // deg + cur

  dim3 b256(256);
  preformat_k<<<36, b256, 0, stream>>>(Wq, Wk, Wv, Wout, Wtq, Wtk, Wpre);

  const int gblk = (N + 63) / 64;
  gemm_mfma_k<float, short, 1><<<gblk, b256, 0, stream>>>(query, Wpre + 0 * 16384, bq, QVp, N);
  gemm_mfma_k<float, short, 0><<<gblk, b256, 0, stream>>>(key,   Wpre + 1 * 16384, bk, Kp, N);
  gemm_mfma_k<float, short, 2><<<gblk, b256, 0, stream>>>(value, Wpre + 2 * 16384, bv, QVp, N);

  temporal_mfma_k<<<2048, b256, 0, stream>>>(temporal, Wpre + 4 * 16384, btq, btk,
                                             tscores, E, (E + 63) / 64);

  count_deg_k<<<(E + 255) / 256, b256, 0, stream>>>(tgt, deg, E);
  block_sum_k<<<G, b256, 0, stream>>>(deg, bsum, N);
  scan_partials_k<<<1, 1024, 0, stream>>>(bsum, boff, G);
  block_scan_k<<<G, b256, 0, stream>>>(deg, boff, off, N);
  scatter_k<<<(E + 255) / 256, b256, 0, stream>>>(src, tgt, off, cur, elist2, E);

  float* attn_w = (float*)d_out + (size_t)N * HID;
  softmax_agg_k<<<(N + 7) / 8, b256, 0, stream>>>(tscores, QVp, Kp, off,
                                                  elist2, attn_w, aggb, N);

  gemm_mfma_k<short, float, 0><<<gblk, b256, 0, stream>>>(aggb, Wpre + 3 * 16384, bout,
                                                          (float*)d_out, N);
}

// Round 9
// 261.601 us; speedup vs baseline: 1.1152x; 1.1152x over previous
//
#include <hip/hip_runtime.h>
#include <hip/hip_bf16.h>

#define HID 128
#define MAXD 64  // per-node fast-path degree cap (Poisson(6) max ~25)

typedef __attribute__((ext_vector_type(8))) short bfrag8;
typedef __attribute__((ext_vector_type(4))) short bf4;
typedef __attribute__((ext_vector_type(4))) float facc4;

// f32 -> bf16 bits, round-to-nearest-even
__device__ inline short f2bf(float x) {
  unsigned u = __builtin_bit_cast(unsigned, x);
  u += 0x7fffu + ((u >> 16) & 1u);
  return (short)(u >> 16);
}
__device__ inline float bf2f(short s) {
  unsigned u = ((unsigned)(unsigned short)s) << 16;
  return __builtin_bit_cast(float, u);
}

__device__ inline void store_val(float* Y, size_t i, float v) { Y[i] = v; }
__device__ inline void store_val(short* Y, size_t i, float v) { Y[i] = f2bf(v); }

// ---------------------------------------------------------------------------
// init_k: zero deg+cur (2N ints) AND pre-format all weights to fragment-linear
// bf16 chunks (one launch replaces memset + preformat).
// Chunks 0..8191: Wq,Wk,Wv,Wout (2048 each), layout ct<<8|kt<<6|g<<4|c.
// Chunks 8192..9215: [Wtq|Wtk] (1024), layout qk<<9|ct<<6|g<<4|c.
// ---------------------------------------------------------------------------
__global__ __launch_bounds__(256) void init_k(
    const float* __restrict__ Wq, const float* __restrict__ Wk,
    const float* __restrict__ Wv, const float* __restrict__ Wout,
    const float* __restrict__ Wtq, const float* __restrict__ Wtk,
    short* __restrict__ out, int* __restrict__ degcur, int n2) {
  int gid = blockIdx.x * 256 + threadIdx.x;
  if (gid < n2) degcur[gid] = 0;
  if (gid >= 9216) return;
  bfrag8 v;
  if (gid < 8192) {
    int which = gid >> 11;
    int chunk = gid & 2047;
    const float* W = (which == 0) ? Wq : (which == 1) ? Wk
                   : (which == 2) ? Wv : Wout;
    int c  = chunk & 15;
    int g  = (chunk >> 4) & 3;
    int kt = (chunk >> 6) & 3;
    int ct = chunk >> 8;
    int col = ct * 16 + c;
    int k0 = kt * 32 + g * 8;
    #pragma unroll
    for (int i = 0; i < 8; ++i) v[i] = f2bf(W[(size_t)(k0 + i) * HID + col]);
  } else {
    int chunk = gid - 8192;
    int c  = chunk & 15;
    int g  = (chunk >> 4) & 3;
    int ct = (chunk >> 6) & 7;
    int qk = chunk >> 9;
    const float* W = qk ? Wtk : Wtq;
    int col = ct * 16 + c;
    int k0 = g * 8;
    #pragma unroll
    for (int i = 0; i < 8; ++i) v[i] = f2bf(W[(size_t)(k0 + i) * HID + col]);
  }
  *(bfrag8*)(out + (size_t)gid * 8) = v;
}

// ---------------------------------------------------------------------------
// GEMM body: Y = X @ W + b via bf16 MFMA, 64 rows per block.
// MODE 0: Y[row*128+col]; MODE 1: Q-pack QV[row*256+(col>>2)*8+(col&3)];
// MODE 2: V-pack (same + 4).
// ---------------------------------------------------------------------------
template <typename IT, typename OT, int MODE>
__device__ __forceinline__ void gemm_body(
    short* __restrict__ Ws, const IT* __restrict__ X,
    const short* __restrict__ Wp, const float* __restrict__ b,
    OT* __restrict__ Y, int nrows, int bx) {
  const int t = threadIdx.x;
  #pragma unroll
  for (int it = 0; it < 8; ++it) {
    int chunk = t + it * 256;
    *(bfrag8*)(&Ws[chunk * 8]) = *(const bfrag8*)(Wp + (size_t)chunk * 8);
  }
  __syncthreads();

  const int w  = t >> 6;
  const int l  = t & 63;
  const int lr = l & 15;
  const int g  = l >> 4;
  const int row0 = bx * 64 + w * 16;
  const int arow = min(row0 + lr, nrows - 1);

  facc4 acc[8];
  #pragma unroll
  for (int i = 0; i < 8; ++i) acc[i] = (facc4){0.f, 0.f, 0.f, 0.f};

  #pragma unroll
  for (int kt = 0; kt < 4; ++kt) {
    bfrag8 a;
    if constexpr (sizeof(IT) == 4) {
      const float* xp = (const float*)X + (size_t)arow * HID + kt * 32 + g * 8;
      float xv[8];
      *(facc4*)(xv)     = *(const facc4*)(xp);
      *(facc4*)(xv + 4) = *(const facc4*)(xp + 4);
      #pragma unroll
      for (int i = 0; i < 8; ++i) a[i] = f2bf(xv[i]);
    } else {
      a = *(const bfrag8*)((const short*)X + (size_t)arow * HID + kt * 32 + g * 8);
    }
    #pragma unroll
    for (int ct = 0; ct < 8; ++ct) {
      bfrag8 bf = *(const bfrag8*)(&Ws[(((ct * 4 + kt) * 4 + g) * 16 + lr) * 8]);
      acc[ct] = __builtin_amdgcn_mfma_f32_16x16x32_bf16(a, bf, acc[ct], 0, 0, 0);
    }
  }

  #pragma unroll
  for (int ct = 0; ct < 8; ++ct) {
    int col = ct * 16 + lr;
    float bias = b[col];
    #pragma unroll
    for (int r = 0; r < 4; ++r) {
      int row = row0 + g * 4 + r;
      if (row < nrows) {
        size_t oidx;
        if constexpr (MODE == 0) oidx = (size_t)row * HID + col;
        else oidx = (size_t)row * 256 + ((col >> 2) << 3) + (col & 3) +
                    (MODE == 2 ? 4 : 0);
        store_val(Y, oidx, acc[ct][r] + bias);
      }
    }
  }
}

// ---------------------------------------------------------------------------
// Temporal body: edges-on-COLUMNS MFMA mapping, persistent over tiles.
// Per-(edge,head) sums parked in a 512B/wave LDS slab (same-wave ordering),
// then one coalesced 8B/lane store writes the full 512B tile row.
// ---------------------------------------------------------------------------
__device__ __forceinline__ void temporal_body(
    short* __restrict__ Ws, float* __restrict__ bsh, float* __restrict__ tsh,
    const float* __restrict__ T, const short* __restrict__ Wp,
    const float* __restrict__ btq, const float* __restrict__ btk,
    float* __restrict__ ts, int E, int ntiles, int bx, int nblk) {
  const int t = threadIdx.x;
  #pragma unroll
  for (int it = 0; it < 4; ++it) {
    int chunk = t + it * 256;
    *(bfrag8*)(&Ws[chunk * 8]) = *(const bfrag8*)(Wp + (size_t)chunk * 8);
  }
  bsh[t] = (t < 128) ? btq[t] : btk[t - 128];
  __syncthreads();

  const int w = t >> 6;
  const int l = t & 63;
  const int c = l & 15;  // edge within 16-edge wave tile (MFMA column)
  const int g = l >> 4;  // feature-row group
  float* mytsh = tsh + w * 128;  // [16 edges][8 heads]

  for (int tile = bx; tile < ntiles; tile += nblk) {
    const int e0 = tile * 64 + w * 16;
    const int ar = min(e0 + c, E - 1);
    const float* tp = T + (size_t)ar * 32 + g * 8;
    float xv[8];
    *(facc4*)(xv)     = *(const facc4*)(tp);
    *(facc4*)(xv + 4) = *(const facc4*)(tp + 4);
    bfrag8 tb;
    #pragma unroll
    for (int i = 0; i < 8; ++i) tb[i] = f2bf(xv[i]);

    #pragma unroll 1
    for (int ct = 0; ct < 8; ++ct) {
      facc4 accq = *(const facc4*)(&bsh[ct * 16 + g * 4]);
      bfrag8 wq = *(const bfrag8*)(&Ws[(ct * 64 + g * 16 + c) * 8]);
      accq = __builtin_amdgcn_mfma_f32_16x16x32_bf16(wq, tb, accq, 0, 0, 0);
      facc4 acck = *(const facc4*)(&bsh[128 + ct * 16 + g * 4]);
      bfrag8 wk = *(const bfrag8*)(&Ws[(512 + ct * 64 + g * 16 + c) * 8]);
      acck = __builtin_amdgcn_mfma_f32_16x16x32_bf16(wk, tb, acck, 0, 0, 0);

      float s = accq[0] * acck[0] + accq[1] * acck[1] +
                accq[2] * acck[2] + accq[3] * acck[3];
      s += __shfl_xor(s, 16, 64);
      s += __shfl_xor(s, 32, 64);
      if (g == 0) mytsh[c * 8 + ct] = s;  // one writer lane per (edge,head)
    }
    // coalesced write: lane l covers edge e0+(l>>2), floats (l&3)*2..+1
    int e = e0 + (l >> 2);
    if (e < E) {
      float2 v2 = *(const float2*)(&mytsh[(l >> 2) * 8 + (l & 3) * 2]);
      *(float2*)(ts + (size_t)e0 * 8 + l * 2) = v2;
    }
  }
}

// ---------------------------------------------------------------------------
// Mega kernel: QKV projections + temporal scores + degree count, one launch.
// Block ranges: [0,gblk) Q | [gblk,2g) K | [2g,3g) V | [3g,3g+2048) temporal
// | rest: count_deg. Uniform per-block branch; 32KB LDS arena reused per role.
// ---------------------------------------------------------------------------
#define TBLK 2048
__global__ __launch_bounds__(256) void mega_k(
    const float* __restrict__ query, const float* __restrict__ key,
    const float* __restrict__ value, const float* __restrict__ temporal,
    const short* __restrict__ Wpre,
    const float* __restrict__ bq, const float* __restrict__ bk,
    const float* __restrict__ bv, const float* __restrict__ btq,
    const float* __restrict__ btk,
    short* __restrict__ QVp, short* __restrict__ Kp,
    float* __restrict__ tscores, const int* __restrict__ tgt,
    int* __restrict__ deg, int N, int E, int gblk, int ntiles) {
  __shared__ __align__(16) char smem[16384 * 2];
  const int bx = blockIdx.x;
  if (bx < gblk) {
    gemm_body<float, short, 1>((short*)smem, query, Wpre + 0 * 16384, bq, QVp, N, bx);
  } else if (bx < 2 * gblk) {
    gemm_body<float, short, 0>((short*)smem, key, Wpre + 1 * 16384, bk, Kp, N, bx - gblk);
  } else if (bx < 3 * gblk) {
    gemm_body<float, short, 2>((short*)smem, value, Wpre + 2 * 16384, bv, QVp, N, bx - 2 * gblk);
  } else if (bx < 3 * gblk + TBLK) {
    temporal_body((short*)smem, (float*)(smem + 16384), (float*)(smem + 16384 + 1024),
                  temporal, Wpre + 4 * 16384, btq, btk, tscores, E, ntiles,
                  bx - 3 * gblk, TBLK);
  } else {
    int gid = (bx - 3 * gblk - TBLK) * 256 + threadIdx.x;
    if (gid < E) atomicAdd(&deg[tgt[gid]], 1);
  }
}

// standalone GEMM for the output projection
template <typename IT, typename OT, int MODE>
__global__ __launch_bounds__(256) void gemm_mfma_k(
    const IT* __restrict__ X, const short* __restrict__ Wp,
    const float* __restrict__ b, OT* __restrict__ Y, int nrows) {
  __shared__ __align__(16) short Ws[16384];
  gemm_body<IT, OT, MODE>(Ws, X, Wp, b, Y, nrows, blockIdx.x);
}

// ---------------------------------------------------------------------------
// CSR scan + scatter
// ---------------------------------------------------------------------------
__global__ __launch_bounds__(256) void block_sum_k(const int* __restrict__ deg,
                                                   int* __restrict__ bsum, int n) {
  __shared__ int sd[256];
  const int base = blockIdx.x * 1024;
  const int t = threadIdx.x;
  int s = 0;
  #pragma unroll
  for (int j = 0; j < 4; ++j) {
    int i = base + t + j * 256;
    if (i < n) s += deg[i];
  }
  sd[t] = s;
  __syncthreads();
  for (int st = 128; st; st >>= 1) {
    if (t < st) sd[t] += sd[t + st];
    __syncthreads();
  }
  if (t == 0) bsum[blockIdx.x] = sd[0];
}

__global__ __launch_bounds__(1024) void scan_partials_k(const int* __restrict__ bsum,
                                                        int* __restrict__ boff, int G) {
  __shared__ int sd[1024];
  const int t = threadIdx.x;
  int v = (t < G) ? bsum[t] : 0;
  sd[t] = v;
  __syncthreads();
  for (int s = 1; s < 1024; s <<= 1) {
    int a = (t >= s) ? sd[t - s] : 0;
    __syncthreads();
    sd[t] += a;
    __syncthreads();
  }
  if (t < G) boff[t] = sd[t] - v;
}

__global__ __launch_bounds__(256) void block_scan_k(const int* __restrict__ deg,
                                                    const int* __restrict__ boff,
                                                    int* __restrict__ off, int n) {
  __shared__ int sd[256];
  const int base = blockIdx.x * 1024;
  const int t = threadIdx.x;
  const int i0 = base + t * 4;
  int v[4];
  int s = 0;
  #pragma unroll
  for (int j = 0; j < 4; ++j) {
    v[j] = (i0 + j < n) ? deg[i0 + j] : 0;
    s += v[j];
  }
  const int own = s;
  sd[t] = s;
  __syncthreads();
  for (int st = 1; st < 256; st <<= 1) {
    int a = (t >= st) ? sd[t - st] : 0;
    __syncthreads();
    sd[t] += a;
    __syncthreads();
  }
  int acc = boff[blockIdx.x] + sd[t] - own;
  #pragma unroll
  for (int j = 0; j < 4; ++j) {
    int idx = i0 + j;
    if (idx < n) {
      off[idx] = acc;
      acc += v[j];
      if (idx == n - 1) off[n] = acc;
    }
  }
}

// writes (edge id, src id) pairs so the softmax kernel never gathers src[]
__global__ __launch_bounds__(256) void scatter_k(const int* __restrict__ src,
                                                 const int* __restrict__ tgt,
                                                 const int* __restrict__ off,
                                                 int* __restrict__ cur,
                                                 int2* __restrict__ elist2, int E) {
  int gid = blockIdx.x * 256 + threadIdx.x;
  if (gid < E) {
    int n = tgt[gid];
    int p = atomicAdd(&cur[n], 1);
    elist2[off[n] + p] = make_int2(gid, src[gid]);
  }
}

// ---------------------------------------------------------------------------
// Per-node QK score + softmax + aggregation, ONE gather pass, no max-tracking
// (scores bounded ~|30| << 88 so fp32 exp is safe; softmax is shift-invariant).
// QV packed rows: lane g reads 16B = {Q feats g*4..+3, V feats g*4..+3}.
// 32 lanes per node, 8 nodes per 256-thread block, no __syncthreads.
// ---------------------------------------------------------------------------
__global__ __launch_bounds__(256) void softmax_agg_k(
    const float* __restrict__ tscores, const short* __restrict__ QVp,
    const short* __restrict__ Kp, const int* __restrict__ off,
    const int2* __restrict__ elist2, float* __restrict__ attn_w,
    short* __restrict__ aggb, int N) {
  __shared__ int esh[8][MAXD];
  __shared__ int ssh[8][MAXD];
  __shared__ float sraw[8][MAXD][8];  // unnormalized exp weights per head
  const int t = threadIdx.x;
  const int grp = t >> 5;
  const int g = t & 31;
  const int h = g >> 2;
  const int j = g & 3;
  const int n = blockIdx.x * 8 + grp;
  if (n >= N) return;

  const int s0 = off[n];
  const int deg = off[n + 1] - s0;

  float kr[4];
  {
    bf4 k4 = *(const bf4*)(Kp + (size_t)n * HID + g * 4);
    #pragma unroll
    for (int q = 0; q < 4; ++q) kr[q] = bf2f(k4[q]);
  }

  if (deg <= MAXD) {
    for (int i = g; i < deg; i += 32) {
      int2 es = elist2[s0 + i];
      esh[grp][i] = es.x;
      ssh[grp][i] = es.y;
    }

    float lsum = 0.f;
    float a0 = 0.f, a1 = 0.f, a2 = 0.f, a3 = 0.f;
    int i = 0;
    for (; i + 4 <= deg; i += 4) {
      bfrag8 qv0 = *(const bfrag8*)(QVp + (size_t)ssh[grp][i]     * 256 + g * 8);
      bfrag8 qv1 = *(const bfrag8*)(QVp + (size_t)ssh[grp][i + 1] * 256 + g * 8);
      bfrag8 qv2 = *(const bfrag8*)(QVp + (size_t)ssh[grp][i + 2] * 256 + g * 8);
      bfrag8 qv3 = *(const bfrag8*)(QVp + (size_t)ssh[grp][i + 3] * 256 + g * 8);
      float ts0 = tscores[(size_t)esh[grp][i]     * 8 + h];
      float ts1 = tscores[(size_t)esh[grp][i + 1] * 8 + h];
      float ts2 = tscores[(size_t)esh[grp][i + 2] * 8 + h];
      float ts3 = tscores[(size_t)esh[grp][i + 3] * 8 + h];
      float p0 = bf2f(qv0[0]) * kr[0] + bf2f(qv0[1]) * kr[1] +
                 bf2f(qv0[2]) * kr[2] + bf2f(qv0[3]) * kr[3];
      float p1 = bf2f(qv1[0]) * kr[0] + bf2f(qv1[1]) * kr[1] +
                 bf2f(qv1[2]) * kr[2] + bf2f(qv1[3]) * kr[3];
      float p2 = bf2f(qv2[0]) * kr[0] + bf2f(qv2[1]) * kr[1] +
                 bf2f(qv2[2]) * kr[2] + bf2f(qv2[3]) * kr[3];
      float p3 = bf2f(qv3[0]) * kr[0] + bf2f(qv3[1]) * kr[1] +
                 bf2f(qv3[2]) * kr[2] + bf2f(qv3[3]) * kr[3];
      p0 += __shfl_xor(p0, 1, 4); p0 += __shfl_xor(p0, 2, 4);
      p1 += __shfl_xor(p1, 1, 4); p1 += __shfl_xor(p1, 2, 4);
      p2 += __shfl_xor(p2, 1, 4); p2 += __shfl_xor(p2, 2, 4);
      p3 += __shfl_xor(p3, 1, 4); p3 += __shfl_xor(p3, 2, 4);
      float w0 = __expf(ts0 + p0 * 0.25f);
      float w1 = __expf(ts1 + p1 * 0.25f);
      float w2 = __expf(ts2 + p2 * 0.25f);
      float w3 = __expf(ts3 + p3 * 0.25f);
      if (j == 0) {
        sraw[grp][i][h]     = w0;
        sraw[grp][i + 1][h] = w1;
        sraw[grp][i + 2][h] = w2;
        sraw[grp][i + 3][h] = w3;
      }
      lsum += (w0 + w1) + (w2 + w3);
      a0 += w0 * bf2f(qv0[4]) + w1 * bf2f(qv1[4]) +
            w2 * bf2f(qv2[4]) + w3 * bf2f(qv3[4]);
      a1 += w0 * bf2f(qv0[5]) + w1 * bf2f(qv1[5]) +
            w2 * bf2f(qv2[5]) + w3 * bf2f(qv3[5]);
      a2 += w0 * bf2f(qv0[6]) + w1 * bf2f(qv1[6]) +
            w2 * bf2f(qv2[6]) + w3 * bf2f(qv3[6]);
      a3 += w0 * bf2f(qv0[7]) + w1 * bf2f(qv1[7]) +
            w2 * bf2f(qv2[7]) + w3 * bf2f(qv3[7]);
    }
    for (; i < deg; ++i) {
      bfrag8 qv0 = *(const bfrag8*)(QVp + (size_t)ssh[grp][i] * 256 + g * 8);
      float ts0 = tscores[(size_t)esh[grp][i] * 8 + h];
      float p0 = bf2f(qv0[0]) * kr[0] + bf2f(qv0[1]) * kr[1] +
                 bf2f(qv0[2]) * kr[2] + bf2f(qv0[3]) * kr[3];
      p0 += __shfl_xor(p0, 1, 4); p0 += __shfl_xor(p0, 2, 4);
      float w0 = __expf(ts0 + p0 * 0.25f);
      if (j == 0) sraw[grp][i][h] = w0;
      lsum += w0;
      a0 += w0 * bf2f(qv0[4]);
      a1 += w0 * bf2f(qv0[5]);
      a2 += w0 * bf2f(qv0[6]);
      a3 += w0 * bf2f(qv0[7]);
    }
    float invl = (lsum > 0.f) ? 1.0f / lsum : 0.f;

    bf4 st;
    st[0] = f2bf(a0 * invl); st[1] = f2bf(a1 * invl);
    st[2] = f2bf(a2 * invl); st[3] = f2bf(a3 * invl);
    *(bf4*)(aggb + (size_t)n * HID + g * 4) = st;

    if (j == 0) {
      for (int q = 0; q < deg; ++q)
        attn_w[(size_t)esh[grp][q] * 8 + h] = sraw[grp][q][h] * invl;
    }
  } else {
    // fallback (deg > MAXD): 3-pass unstaged, max-subtracted
    float m = -3.0e38f;
    for (int q = 0; q < deg; ++q) {
      int2 es = elist2[s0 + q];
      bfrag8 q4 = *(const bfrag8*)(QVp + (size_t)es.y * 256 + g * 8);
      float p = bf2f(q4[0]) * kr[0] + bf2f(q4[1]) * kr[1] +
                bf2f(q4[2]) * kr[2] + bf2f(q4[3]) * kr[3];
      p += __shfl_xor(p, 1, 4); p += __shfl_xor(p, 2, 4);
      m = fmaxf(m, tscores[(size_t)es.x * 8 + h] + p * 0.25f);
    }
    float l = 0.f;
    for (int q = 0; q < deg; ++q) {
      int2 es = elist2[s0 + q];
      bfrag8 q4 = *(const bfrag8*)(QVp + (size_t)es.y * 256 + g * 8);
      float p = bf2f(q4[0]) * kr[0] + bf2f(q4[1]) * kr[1] +
                bf2f(q4[2]) * kr[2] + bf2f(q4[3]) * kr[3];
      p += __shfl_xor(p, 1, 4); p += __shfl_xor(p, 2, 4);
      l += __expf(tscores[(size_t)es.x * 8 + h] + p * 0.25f - m);
    }
    float invl = (l > 0.f) ? 1.0f / l : 0.f;
    float a0 = 0.f, a1 = 0.f, a2 = 0.f, a3 = 0.f;
    for (int q = 0; q < deg; ++q) {
      int2 es = elist2[s0 + q];
      bfrag8 q4 = *(const bfrag8*)(QVp + (size_t)es.y * 256 + g * 8);
      float p = bf2f(q4[0]) * kr[0] + bf2f(q4[1]) * kr[1] +
                bf2f(q4[2]) * kr[2] + bf2f(q4[3]) * kr[3];
      p += __shfl_xor(p, 1, 4); p += __shfl_xor(p, 2, 4);
      float w = __expf(tscores[(size_t)es.x * 8 + h] + p * 0.25f - m) * invl;
      a0 += w * bf2f(q4[4]);
      a1 += w * bf2f(q4[5]);
      a2 += w * bf2f(q4[6]);
      a3 += w * bf2f(q4[7]);
      if (j == 0) attn_w[(size_t)es.x * 8 + h] = w;
    }
    bf4 st;
    st[0] = f2bf(a0); st[1] = f2bf(a1); st[2] = f2bf(a2); st[3] = f2bf(a3);
    *(bf4*)(aggb + (size_t)n * HID + g * 4) = st;
  }
}

// ---------------------------------------------------------------------------
extern "C" void kernel_launch(void* const* d_in, const int* in_sizes, int n_in,
                              void* d_out, int out_size, void* d_ws, size_t ws_size,
                              hipStream_t stream) {
  const float* query    = (const float*)d_in[0];
  const float* key      = (const float*)d_in[1];
  const float* value    = (const float*)d_in[2];
  const float* temporal = (const float*)d_in[3];
  const int*   eidx     = (const int*)d_in[4];
  const float* Wq   = (const float*)d_in[5];
  const float* bq   = (const float*)d_in[6];
  const float* Wk   = (const float*)d_in[7];
  const float* bk   = (const float*)d_in[8];
  const float* Wv   = (const float*)d_in[9];
  const float* bv   = (const float*)d_in[10];
  const float* Wtq  = (const float*)d_in[11];
  const float* btq  = (const float*)d_in[12];
  const float* Wtk  = (const float*)d_in[13];
  const float* btk  = (const float*)d_in[14];
  const float* Wout = (const float*)d_in[15];
  const float* bout = (const float*)d_in[16];

  const int N = in_sizes[0] / HID;
  const int E = in_sizes[4] / 2;
  const int* src = eidx;
  const int* tgt = eidx + E;

  char* ws = (char*)d_ws;
  short* QVp = (short*)ws;                     ws += (size_t)N * 256 * 2;
  short* Kp = (short*)ws;                      ws += (size_t)N * HID * 2;
  short* aggb = (short*)ws;                    ws += (size_t)N * HID * 2;
  float* tscores = (float*)ws;                 ws += (size_t)E * 8 * 4;
  int* deg   = (int*)ws;                       ws += (size_t)N * 4;
  int* cur   = (int*)ws;                       ws += (size_t)N * 4;
  int* off   = (int*)ws;                       ws += (size_t)(N + 2) * 4;  // pad->8B align
  int2* elist2 = (int2*)ws;                    ws += (size_t)E * 8;
  int* bsum  = (int*)ws;                       ws += 1024 * 4;
  int* boff  = (int*)ws;                       ws += 1024 * 4;
  short* Wpre = (short*)ws;                    // 9216 * 16B

  const int G = (N + 1023) / 1024;
  const int gblk = (N + 63) / 64;
  const int ntiles = (E + 63) / 64;
  const int cblk = (E + 255) / 256;

  dim3 b256(256);
  // init: zero deg+cur and preformat weights
  init_k<<<(2 * N + 255) / 256, b256, 0, stream>>>(Wq, Wk, Wv, Wout, Wtq, Wtk,
                                                   Wpre, deg, 2 * N);
  // mega: QKV projections + temporal scores + degree count
  mega_k<<<3 * gblk + TBLK + cblk, b256, 0, stream>>>(
      query, key, value, temporal, Wpre, bq, bk, bv, btq, btk,
      QVp, Kp, tscores, tgt, deg, N, E, gblk, ntiles);

  block_sum_k<<<G, b256, 0, stream>>>(deg, bsum, N);
  scan_partials_k<<<1, 1024, 0, stream>>>(bsum, boff, G);
  block_scan_k<<<G, b256, 0, stream>>>(deg, boff, off, N);
  scatter_k<<<cblk, b256, 0, stream>>>(src, tgt, off, cur, elist2, E);

  float* attn_w = (float*)d_out + (size_t)N * HID;
  softmax_agg_k<<<(N + 7) / 8, b256, 0, stream>>>(tscores, QVp, Kp, off,
                                                  elist2, attn_w, aggb, N);

  gemm_mfma_k<short, float, 0><<<gblk, b256, 0, stream>>>(aggb, Wpre + 3 * 16384, bout,
                                                          (float*)d_out, N);
}

// Round 10
// 254.150 us; speedup vs baseline: 1.1479x; 1.0293x over previous
//
#include <hip/hip_runtime.h>
#include <hip/hip_bf16.h>

#define HID 128
#define MAXD 64   // per-node fast-path degree cap (Poisson(6) max ~25)
#define TBLK 2048
#define CH 4      // GEMM chunks (64 rows each) per block

typedef __attribute__((ext_vector_type(8))) short bfrag8;
typedef __attribute__((ext_vector_type(4))) short bf4;
typedef __attribute__((ext_vector_type(4))) float facc4;

// f32 -> bf16 bits, round-to-nearest-even
__device__ inline short f2bf(float x) {
  unsigned u = __builtin_bit_cast(unsigned, x);
  u += 0x7fffu + ((u >> 16) & 1u);
  return (short)(u >> 16);
}
__device__ inline float bf2f(short s) {
  unsigned u = ((unsigned)(unsigned short)s) << 16;
  return __builtin_bit_cast(float, u);
}

// ---------------------------------------------------------------------------
// init_k: zero deg+cur (2N ints) AND pre-format weights to fragment-linear
// bf16 chunks. Chunks 0..8191: Wq,Wk,Wv,Wout (2048 each), layout
// ct<<8|kt<<6|g<<4|c. Chunks 8192..9215: [Wtq|Wtk], layout qk<<9|ct<<6|g<<4|c.
// ---------------------------------------------------------------------------
__global__ __launch_bounds__(256) void init_k(
    const float* __restrict__ Wq, const float* __restrict__ Wk,
    const float* __restrict__ Wv, const float* __restrict__ Wout,
    const float* __restrict__ Wtq, const float* __restrict__ Wtk,
    short* __restrict__ out, int* __restrict__ degcur, int n2) {
  int gid = blockIdx.x * 256 + threadIdx.x;
  if (gid < n2) degcur[gid] = 0;
  if (gid >= 9216) return;
  bfrag8 v;
  if (gid < 8192) {
    int which = gid >> 11;
    int chunk = gid & 2047;
    const float* W = (which == 0) ? Wq : (which == 1) ? Wk
                   : (which == 2) ? Wv : Wout;
    int c  = chunk & 15;
    int g  = (chunk >> 4) & 3;
    int kt = (chunk >> 6) & 3;
    int ct = chunk >> 8;
    int col = ct * 16 + c;
    int k0 = kt * 32 + g * 8;
    #pragma unroll
    for (int i = 0; i < 8; ++i) v[i] = f2bf(W[(size_t)(k0 + i) * HID + col]);
  } else {
    int chunk = gid - 8192;
    int c  = chunk & 15;
    int g  = (chunk >> 4) & 3;
    int ct = (chunk >> 6) & 7;
    int qk = chunk >> 9;
    const float* W = qk ? Wtk : Wtq;
    int col = ct * 16 + c;
    int k0 = g * 8;
    #pragma unroll
    for (int i = 0; i < 8; ++i) v[i] = f2bf(W[(size_t)(k0 + i) * HID + col]);
  }
  *(bfrag8*)(out + (size_t)gid * 8) = v;
}

// ---------------------------------------------------------------------------
// GEMM body, SWAPPED operands (A = W fragment, B = X fragment):
// lane (lr=l&15, g=l>>4) owns output row row0+lr, cols ct*16+g*4..+3
// -> dense 8B/16B stores. W staged once per block; CH chunks via grid-stride.
// MODE 0: Y[row*128+col]; MODE 1: QV Q-half [row*256+col];
// MODE 2: QV V-half [row*256+128+col].
// ---------------------------------------------------------------------------
template <typename IT, typename OT, int MODE>
__device__ __forceinline__ void gemm_body(
    short* __restrict__ Ws, const IT* __restrict__ X,
    const short* __restrict__ Wp, const float* __restrict__ b,
    OT* __restrict__ Y, int nrows, int bx0, int stride, int nchunks) {
  const int t = threadIdx.x;
  #pragma unroll
  for (int it = 0; it < 8; ++it) {
    int chunk = t + it * 256;
    *(bfrag8*)(&Ws[chunk * 8]) = *(const bfrag8*)(Wp + (size_t)chunk * 8);
  }
  __syncthreads();

  const int w  = t >> 6;
  const int l  = t & 63;
  const int lr = l & 15;
  const int g  = l >> 4;

  for (int ch = bx0; ch < nchunks; ch += stride) {
    const int row0 = ch * 64 + w * 16;
    const int arow = min(row0 + lr, nrows - 1);

    facc4 acc[8];
    #pragma unroll
    for (int i = 0; i < 8; ++i) acc[i] = (facc4){0.f, 0.f, 0.f, 0.f};

    #pragma unroll
    for (int kt = 0; kt < 4; ++kt) {
      bfrag8 a;
      if constexpr (sizeof(IT) == 4) {
        const float* xp = (const float*)X + (size_t)arow * HID + kt * 32 + g * 8;
        float xv[8];
        *(facc4*)(xv)     = *(const facc4*)(xp);
        *(facc4*)(xv + 4) = *(const facc4*)(xp + 4);
        #pragma unroll
        for (int i = 0; i < 8; ++i) a[i] = f2bf(xv[i]);
      } else {
        a = *(const bfrag8*)((const short*)X + (size_t)arow * HID + kt * 32 + g * 8);
      }
      #pragma unroll
      for (int ct = 0; ct < 8; ++ct) {
        bfrag8 bf = *(const bfrag8*)(&Ws[(((ct * 4 + kt) * 4 + g) * 16 + lr) * 8]);
        acc[ct] = __builtin_amdgcn_mfma_f32_16x16x32_bf16(bf, a, acc[ct], 0, 0, 0);
      }
    }

    const int row = row0 + lr;
    if (row < nrows) {
      #pragma unroll
      for (int ct = 0; ct < 8; ++ct) {
        const int col0 = ct * 16 + g * 4;
        facc4 bias = *(const facc4*)(b + col0);
        facc4 v;
        #pragma unroll
        for (int j = 0; j < 4; ++j) v[j] = acc[ct][j] + bias[j];
        if constexpr (sizeof(OT) == 4) {
          *(facc4*)((float*)Y + (size_t)row * HID + col0) = v;
        } else {
          bf4 p;
          #pragma unroll
          for (int j = 0; j < 4; ++j) p[j] = f2bf(v[j]);
          size_t base;
          if constexpr (MODE == 0) base = (size_t)row * HID + col0;
          else base = (size_t)row * 256 + col0 + (MODE == 2 ? 128 : 0);
          *(bf4*)((short*)Y + base) = p;
        }
      }
    }
  }
}

// ---------------------------------------------------------------------------
// Temporal body: edges-on-COLUMNS MFMA (A=W, B=T^T). Per-(edge,head) sums
// parked in a padded LDS slab (stride 10 floats -> <=2-way banks, aligned
// float2), then one coalesced 8B/lane store per tile.
// ---------------------------------------------------------------------------
__device__ __forceinline__ void temporal_body(
    short* __restrict__ Ws, float* __restrict__ bsh, float* __restrict__ tsh,
    const float* __restrict__ T, const short* __restrict__ Wp,
    const float* __restrict__ btq, const float* __restrict__ btk,
    float* __restrict__ ts, int E, int ntiles, int bx, int nblk) {
  const int t = threadIdx.x;
  #pragma unroll
  for (int it = 0; it < 4; ++it) {
    int chunk = t + it * 256;
    *(bfrag8*)(&Ws[chunk * 8]) = *(const bfrag8*)(Wp + (size_t)chunk * 8);
  }
  bsh[t] = (t < 128) ? btq[t] : btk[t - 128];
  __syncthreads();

  const int w = t >> 6;
  const int l = t & 63;
  const int c = l & 15;  // edge within 16-edge wave tile
  const int g = l >> 4;  // feature-row group
  float* mytsh = tsh + w * 160;  // [16 edges][10] padded

  for (int tile = bx; tile < ntiles; tile += nblk) {
    const int e0 = tile * 64 + w * 16;
    const int ar = min(e0 + c, E - 1);
    const float* tp = T + (size_t)ar * 32 + g * 8;
    float xv[8];
    *(facc4*)(xv)     = *(const facc4*)(tp);
    *(facc4*)(xv + 4) = *(const facc4*)(tp + 4);
    bfrag8 tb;
    #pragma unroll
    for (int i = 0; i < 8; ++i) tb[i] = f2bf(xv[i]);

    #pragma unroll 1
    for (int ct = 0; ct < 8; ++ct) {
      facc4 accq = *(const facc4*)(&bsh[ct * 16 + g * 4]);
      bfrag8 wq = *(const bfrag8*)(&Ws[(ct * 64 + g * 16 + c) * 8]);
      accq = __builtin_amdgcn_mfma_f32_16x16x32_bf16(wq, tb, accq, 0, 0, 0);
      facc4 acck = *(const facc4*)(&bsh[128 + ct * 16 + g * 4]);
      bfrag8 wk = *(const bfrag8*)(&Ws[(512 + ct * 64 + g * 16 + c) * 8]);
      acck = __builtin_amdgcn_mfma_f32_16x16x32_bf16(wk, tb, acck, 0, 0, 0);

      float s = accq[0] * acck[0] + accq[1] * acck[1] +
                accq[2] * acck[2] + accq[3] * acck[3];
      s += __shfl_xor(s, 16, 64);
      s += __shfl_xor(s, 32, 64);
      if (g == 0) mytsh[c * 10 + ct] = s;
    }
    // coalesced write: lane l covers edge e0+(l>>2), heads (l&3)*2..+1
    int e = e0 + (l >> 2);
    if (e < E) {
      float2 v2 = *(const float2*)(&mytsh[(l >> 2) * 10 + (l & 3) * 2]);
      *(float2*)(ts + (size_t)e0 * 8 + l * 2) = v2;
    }
  }
}

// ---------------------------------------------------------------------------
// Mega kernel: QKV projections + temporal scores + degree count, one launch.
// ---------------------------------------------------------------------------
__global__ __launch_bounds__(256) void mega_k(
    const float* __restrict__ query, const float* __restrict__ key,
    const float* __restrict__ value, const float* __restrict__ temporal,
    const short* __restrict__ Wpre,
    const float* __restrict__ bq, const float* __restrict__ bk,
    const float* __restrict__ bv, const float* __restrict__ btq,
    const float* __restrict__ btk,
    short* __restrict__ QVp, short* __restrict__ Kp,
    float* __restrict__ tscores, const int* __restrict__ tgt,
    int* __restrict__ deg, int N, int E, int gq, int gblk, int ntiles) {
  __shared__ __align__(16) char smem[32768];
  const int bx = blockIdx.x;
  if (bx < gq) {
    gemm_body<float, short, 1>((short*)smem, query, Wpre + 0 * 16384, bq, QVp,
                               N, bx, gq, gblk);
  } else if (bx < 2 * gq) {
    gemm_body<float, short, 0>((short*)smem, key, Wpre + 1 * 16384, bk, Kp,
                               N, bx - gq, gq, gblk);
  } else if (bx < 3 * gq) {
    gemm_body<float, short, 2>((short*)smem, value, Wpre + 2 * 16384, bv, QVp,
                               N, bx - 2 * gq, gq, gblk);
  } else if (bx < 3 * gq + TBLK) {
    temporal_body((short*)smem, (float*)(smem + 16384),
                  (float*)(smem + 16384 + 1024),
                  temporal, Wpre + 4 * 16384, btq, btk, tscores, E, ntiles,
                  bx - 3 * gq, TBLK);
  } else {
    int gid = (bx - 3 * gq - TBLK) * 256 + threadIdx.x;
    if (gid < E) atomicAdd(&deg[tgt[gid]], 1);
  }
}

// standalone GEMM for the output projection
template <typename IT, typename OT, int MODE>
__global__ __launch_bounds__(256) void gemm_mfma_k(
    const IT* __restrict__ X, const short* __restrict__ Wp,
    const float* __restrict__ b, OT* __restrict__ Y, int nrows,
    int stride, int nchunks) {
  __shared__ __align__(16) short Ws[16384];
  gemm_body<IT, OT, MODE>(Ws, X, Wp, b, Y, nrows, blockIdx.x, stride, nchunks);
}

// ---------------------------------------------------------------------------
// CSR scan + scatter
// ---------------------------------------------------------------------------
__global__ __launch_bounds__(256) void block_sum_k(const int* __restrict__ deg,
                                                   int* __restrict__ bsum, int n) {
  __shared__ int sd[256];
  const int base = blockIdx.x * 1024;
  const int t = threadIdx.x;
  int s = 0;
  #pragma unroll
  for (int j = 0; j < 4; ++j) {
    int i = base + t + j * 256;
    if (i < n) s += deg[i];
  }
  sd[t] = s;
  __syncthreads();
  for (int st = 128; st; st >>= 1) {
    if (t < st) sd[t] += sd[t + st];
    __syncthreads();
  }
  if (t == 0) bsum[blockIdx.x] = sd[0];
}

__global__ __launch_bounds__(1024) void scan_partials_k(const int* __restrict__ bsum,
                                                        int* __restrict__ boff, int G) {
  __shared__ int sd[1024];
  const int t = threadIdx.x;
  int v = (t < G) ? bsum[t] : 0;
  sd[t] = v;
  __syncthreads();
  for (int s = 1; s < 1024; s <<= 1) {
    int a = (t >= s) ? sd[t - s] : 0;
    __syncthreads();
    sd[t] += a;
    __syncthreads();
  }
  if (t < G) boff[t] = sd[t] - v;
}

__global__ __launch_bounds__(256) void block_scan_k(const int* __restrict__ deg,
                                                    const int* __restrict__ boff,
                                                    int* __restrict__ off, int n) {
  __shared__ int sd[256];
  const int base = blockIdx.x * 1024;
  const int t = threadIdx.x;
  const int i0 = base + t * 4;
  int v[4];
  int s = 0;
  #pragma unroll
  for (int j = 0; j < 4; ++j) {
    v[j] = (i0 + j < n) ? deg[i0 + j] : 0;
    s += v[j];
  }
  const int own = s;
  sd[t] = s;
  __syncthreads();
  for (int st = 1; st < 256; st <<= 1) {
    int a = (t >= st) ? sd[t - st] : 0;
    __syncthreads();
    sd[t] += a;
    __syncthreads();
  }
  int acc = boff[blockIdx.x] + sd[t] - own;
  #pragma unroll
  for (int j = 0; j < 4; ++j) {
    int idx = i0 + j;
    if (idx < n) {
      off[idx] = acc;
      acc += v[j];
      if (idx == n - 1) off[n] = acc;
    }
  }
}

// writes (edge id, src id) pairs so the softmax kernel never gathers src[]
__global__ __launch_bounds__(256) void scatter_k(const int* __restrict__ src,
                                                 const int* __restrict__ tgt,
                                                 const int* __restrict__ off,
                                                 int* __restrict__ cur,
                                                 int2* __restrict__ elist2, int E) {
  int gid = blockIdx.x * 256 + threadIdx.x;
  if (gid < E) {
    int n = tgt[gid];
    int p = atomicAdd(&cur[n], 1);
    elist2[off[n] + p] = make_int2(gid, src[gid]);
  }
}

// ---------------------------------------------------------------------------
// Per-node QK score + softmax + aggregation, ONE gather pass, no max-tracking
// (scores bounded ~|30| << 88; softmax is shift-invariant).
// QV rows [Q128|V128]: lane g reads 8B q at +g*4 and 8B v at +128+g*4.
// 32 lanes per node, 8 nodes per 256-thread block, no __syncthreads.
// ---------------------------------------------------------------------------
__global__ __launch_bounds__(256) void softmax_agg_k(
    const float* __restrict__ tscores, const short* __restrict__ QVp,
    const short* __restrict__ Kp, const int* __restrict__ off,
    const int2* __restrict__ elist2, float* __restrict__ attn_w,
    short* __restrict__ aggb, int N) {
  __shared__ int esh[8][MAXD];
  __shared__ int ssh[8][MAXD];
  __shared__ float sraw[8][MAXD][8];  // unnormalized exp weights per head
  const int t = threadIdx.x;
  const int grp = t >> 5;
  const int g = t & 31;
  const int h = g >> 2;
  const int j = g & 3;
  const int n = blockIdx.x * 8 + grp;
  if (n >= N) return;

  const int s0 = off[n];
  const int deg = off[n + 1] - s0;

  float kr[4];
  {
    bf4 k4 = *(const bf4*)(Kp + (size_t)n * HID + g * 4);
    #pragma unroll
    for (int q = 0; q < 4; ++q) kr[q] = bf2f(k4[q]);
  }

  if (deg <= MAXD) {
    for (int i = g; i < deg; i += 32) {
      int2 es = elist2[s0 + i];
      esh[grp][i] = es.x;
      ssh[grp][i] = es.y;
    }

    float lsum = 0.f;
    float a0 = 0.f, a1 = 0.f, a2 = 0.f, a3 = 0.f;
    int i = 0;
    for (; i + 4 <= deg; i += 4) {
      const size_t b0 = (size_t)ssh[grp][i]     * 256 + g * 4;
      const size_t b1 = (size_t)ssh[grp][i + 1] * 256 + g * 4;
      const size_t b2 = (size_t)ssh[grp][i + 2] * 256 + g * 4;
      const size_t b3 = (size_t)ssh[grp][i + 3] * 256 + g * 4;
      bf4 q0 = *(const bf4*)(QVp + b0);
      bf4 q1 = *(const bf4*)(QVp + b1);
      bf4 q2 = *(const bf4*)(QVp + b2);
      bf4 q3 = *(const bf4*)(QVp + b3);
      bf4 v0 = *(const bf4*)(QVp + b0 + 128);
      bf4 v1 = *(const bf4*)(QVp + b1 + 128);
      bf4 v2 = *(const bf4*)(QVp + b2 + 128);
      bf4 v3 = *(const bf4*)(QVp + b3 + 128);
      float ts0 = tscores[(size_t)esh[grp][i]     * 8 + h];
      float ts1 = tscores[(size_t)esh[grp][i + 1] * 8 + h];
      float ts2 = tscores[(size_t)esh[grp][i + 2] * 8 + h];
      float ts3 = tscores[(size_t)esh[grp][i + 3] * 8 + h];
      float p0 = bf2f(q0[0]) * kr[0] + bf2f(q0[1]) * kr[1] +
                 bf2f(q0[2]) * kr[2] + bf2f(q0[3]) * kr[3];
      float p1 = bf2f(q1[0]) * kr[0] + bf2f(q1[1]) * kr[1] +
                 bf2f(q1[2]) * kr[2] + bf2f(q1[3]) * kr[3];
      float p2 = bf2f(q2[0]) * kr[0] + bf2f(q2[1]) * kr[1] +
                 bf2f(q2[2]) * kr[2] + bf2f(q2[3]) * kr[3];
      float p3 = bf2f(q3[0]) * kr[0] + bf2f(q3[1]) * kr[1] +
                 bf2f(q3[2]) * kr[2] + bf2f(q3[3]) * kr[3];
      p0 += __shfl_xor(p0, 1, 4); p0 += __shfl_xor(p0, 2, 4);
      p1 += __shfl_xor(p1, 1, 4); p1 += __shfl_xor(p1, 2, 4);
      p2 += __shfl_xor(p2, 1, 4); p2 += __shfl_xor(p2, 2, 4);
      p3 += __shfl_xor(p3, 1, 4); p3 += __shfl_xor(p3, 2, 4);
      float w0 = __expf(ts0 + p0 * 0.25f);
      float w1 = __expf(ts1 + p1 * 0.25f);
      float w2 = __expf(ts2 + p2 * 0.25f);
      float w3 = __expf(ts3 + p3 * 0.25f);
      if (j == 0) {
        sraw[grp][i][h]     = w0;
        sraw[grp][i + 1][h] = w1;
        sraw[grp][i + 2][h] = w2;
        sraw[grp][i + 3][h] = w3;
      }
      lsum += (w0 + w1) + (w2 + w3);
      a0 += w0 * bf2f(v0[0]) + w1 * bf2f(v1[0]) +
            w2 * bf2f(v2[0]) + w3 * bf2f(v3[0]);
      a1 += w0 * bf2f(v0[1]) + w1 * bf2f(v1[1]) +
            w2 * bf2f(v2[1]) + w3 * bf2f(v3[1]);
      a2 += w0 * bf2f(v0[2]) + w1 * bf2f(v1[2]) +
            w2 * bf2f(v2[2]) + w3 * bf2f(v3[2]);
      a3 += w0 * bf2f(v0[3]) + w1 * bf2f(v1[3]) +
            w2 * bf2f(v2[3]) + w3 * bf2f(v3[3]);
    }
    for (; i < deg; ++i) {
      const size_t b0 = (size_t)ssh[grp][i] * 256 + g * 4;
      bf4 q0 = *(const bf4*)(QVp + b0);
      bf4 v0 = *(const bf4*)(QVp + b0 + 128);
      float ts0 = tscores[(size_t)esh[grp][i] * 8 + h];
      float p0 = bf2f(q0[0]) * kr[0] + bf2f(q0[1]) * kr[1] +
                 bf2f(q0[2]) * kr[2] + bf2f(q0[3]) * kr[3];
      p0 += __shfl_xor(p0, 1, 4); p0 += __shfl_xor(p0, 2, 4);
      float w0 = __expf(ts0 + p0 * 0.25f);
      if (j == 0) sraw[grp][i][h] = w0;
      lsum += w0;
      a0 += w0 * bf2f(v0[0]);
      a1 += w0 * bf2f(v0[1]);
      a2 += w0 * bf2f(v0[2]);
      a3 += w0 * bf2f(v0[3]);
    }
    float invl = (lsum > 0.f) ? 1.0f / lsum : 0.f;

    bf4 st;
    st[0] = f2bf(a0 * invl); st[1] = f2bf(a1 * invl);
    st[2] = f2bf(a2 * invl); st[3] = f2bf(a3 * invl);
    *(bf4*)(aggb + (size_t)n * HID + g * 4) = st;

    if (j == 0) {
      for (int q = 0; q < deg; ++q)
        attn_w[(size_t)esh[grp][q] * 8 + h] = sraw[grp][q][h] * invl;
    }
  } else {
    // fallback (deg > MAXD): 3-pass unstaged, max-subtracted
    float m = -3.0e38f;
    for (int q = 0; q < deg; ++q) {
      int2 es = elist2[s0 + q];
      bf4 q4 = *(const bf4*)(QVp + (size_t)es.y * 256 + g * 4);
      float p = bf2f(q4[0]) * kr[0] + bf2f(q4[1]) * kr[1] +
                bf2f(q4[2]) * kr[2] + bf2f(q4[3]) * kr[3];
      p += __shfl_xor(p, 1, 4); p += __shfl_xor(p, 2, 4);
      m = fmaxf(m, tscores[(size_t)es.x * 8 + h] + p * 0.25f);
    }
    float l = 0.f;
    for (int q = 0; q < deg; ++q) {
      int2 es = elist2[s0 + q];
      bf4 q4 = *(const bf4*)(QVp + (size_t)es.y * 256 + g * 4);
      float p = bf2f(q4[0]) * kr[0] + bf2f(q4[1]) * kr[1] +
                bf2f(q4[2]) * kr[2] + bf2f(q4[3]) * kr[3];
      p += __shfl_xor(p, 1, 4); p += __shfl_xor(p, 2, 4);
      l += __expf(tscores[(size_t)es.x * 8 + h] + p * 0.25f - m);
    }
    float invl = (l > 0.f) ? 1.0f / l : 0.f;
    float a0 = 0.f, a1 = 0.f, a2 = 0.f, a3 = 0.f;
    for (int q = 0; q < deg; ++q) {
      int2 es = elist2[s0 + q];
      bf4 q4 = *(const bf4*)(QVp + (size_t)es.y * 256 + g * 4);
      bf4 v4 = *(const bf4*)(QVp + (size_t)es.y * 256 + 128 + g * 4);
      float p = bf2f(q4[0]) * kr[0] + bf2f(q4[1]) * kr[1] +
                bf2f(q4[2]) * kr[2] + bf2f(q4[3]) * kr[3];
      p += __shfl_xor(p, 1, 4); p += __shfl_xor(p, 2, 4);
      float w = __expf(tscores[(size_t)es.x * 8 + h] + p * 0.25f - m) * invl;
      a0 += w * bf2f(v4[0]);
      a1 += w * bf2f(v4[1]);
      a2 += w * bf2f(v4[2]);
      a3 += w * bf2f(v4[3]);
      if (j == 0) attn_w[(size_t)es.x * 8 + h] = w;
    }
    bf4 st;
    st[0] = f2bf(a0); st[1] = f2bf(a1); st[2] = f2bf(a2); st[3] = f2bf(a3);
    *(bf4*)(aggb + (size_t)n * HID + g * 4) = st;
  }
}

// ---------------------------------------------------------------------------
extern "C" void kernel_launch(void* const* d_in, const int* in_sizes, int n_in,
                              void* d_out, int out_size, void* d_ws, size_t ws_size,
                              hipStream_t stream) {
  const float* query    = (const float*)d_in[0];
  const float* key      = (const float*)d_in[1];
  const float* value    = (const float*)d_in[2];
  const float* temporal = (const float*)d_in[3];
  const int*   eidx     = (const int*)d_in[4];
  const float* Wq   = (const float*)d_in[5];
  const float* bq   = (const float*)d_in[6];
  const float* Wk   = (const float*)d_in[7];
  const float* bk   = (const float*)d_in[8];
  const float* Wv   = (const float*)d_in[9];
  const float* bv   = (const float*)d_in[10];
  const float* Wtq  = (const float*)d_in[11];
  const float* btq  = (const float*)d_in[12];
  const float* Wtk  = (const float*)d_in[13];
  const float* btk  = (const float*)d_in[14];
  const float* Wout = (const float*)d_in[15];
  const float* bout = (const float*)d_in[16];

  const int N = in_sizes[0] / HID;
  const int E = in_sizes[4] / 2;
  const int* src = eidx;
  const int* tgt = eidx + E;

  char* ws = (char*)d_ws;
  short* QVp = (short*)ws;                     ws += (size_t)N * 256 * 2;
  short* Kp = (short*)ws;                      ws += (size_t)N * HID * 2;
  short* aggb = (short*)ws;                    ws += (size_t)N * HID * 2;
  float* tscores = (float*)ws;                 ws += (size_t)E * 8 * 4;
  int* deg   = (int*)ws;                       ws += (size_t)N * 4;
  int* cur   = (int*)ws;                       ws += (size_t)N * 4;
  int* off   = (int*)ws;                       ws += (size_t)(N + 2) * 4;  // pad->8B align
  int2* elist2 = (int2*)ws;                    ws += (size_t)E * 8;
  int* bsum  = (int*)ws;                       ws += 1024 * 4;
  int* boff  = (int*)ws;                       ws += 1024 * 4;
  short* Wpre = (short*)ws;                    // 9216 * 16B

  const int G = (N + 1023) / 1024;
  const int gblk = (N + 63) / 64;
  const int gq = (gblk + CH - 1) / CH;
  const int ntiles = (E + 63) / 64;
  const int cblk = (E + 255) / 256;

  dim3 b256(256);
  init_k<<<(2 * N + 255) / 256, b256, 0, stream>>>(Wq, Wk, Wv, Wout, Wtq, Wtk,
                                                   Wpre, deg, 2 * N);
  mega_k<<<3 * gq + TBLK + cblk, b256, 0, stream>>>(
      query, key, value, temporal, Wpre, bq, bk, bv, btq, btk,
      QVp, Kp, tscores, tgt, deg, N, E, gq, gblk, ntiles);

  block_sum_k<<<G, b256, 0, stream>>>(deg, bsum, N);
  scan_partials_k<<<1, 1024, 0, stream>>>(bsum, boff, G);
  block_scan_k<<<G, b256, 0, stream>>>(deg, boff, off, N);
  scatter_k<<<cblk, b256, 0, stream>>>(src, tgt, off, cur, elist2, E);

  float* attn_w = (float*)d_out + (size_t)N * HID;
  softmax_agg_k<<<(N + 7) / 8, b256, 0, stream>>>(tscores, QVp, Kp, off,
                                                  elist2, attn_w, aggb, N);

  gemm_mfma_k<short, float, 0><<<gq, b256, 0, stream>>>(aggb, Wpre + 3 * 16384,
                                                        bout, (float*)d_out, N,
                                                        gq, gblk);
}

// Round 11
// 222.806 us; speedup vs baseline: 1.3094x; 1.1407x over previous
//
#include <hip/hip_runtime.h>
#include <hip/hip_bf16.h>

#define HID 128
#define MAXD 64   // per-node fast-path degree cap (Poisson(6) max ~25)
#define TBLK 1024 // persistent temporal blocks (512 threads each)
#define CH 4      // GEMM chunks (128 rows each) per block

typedef __attribute__((ext_vector_type(8))) short bfrag8;
typedef __attribute__((ext_vector_type(4))) short bf4;
typedef __attribute__((ext_vector_type(4))) float facc4;

// f32 -> bf16 bits, round-to-nearest-even
__device__ inline short f2bf(float x) {
  unsigned u = __builtin_bit_cast(unsigned, x);
  u += 0x7fffu + ((u >> 16) & 1u);
  return (short)(u >> 16);
}
__device__ inline float bf2f(short s) {
  unsigned u = ((unsigned)(unsigned short)s) << 16;
  return __builtin_bit_cast(float, u);
}

// ---------------------------------------------------------------------------
// init_k: zero deg+cur (2N ints) AND pre-format weights to fragment-linear
// bf16 chunks. Chunks 0..8191: Wq,Wk,Wv,Wout (2048 each), layout
// ct<<8|kt<<6|g<<4|c. Chunks 8192..9215: [Wtq|Wtk], layout qk<<9|ct<<6|g<<4|c.
// ---------------------------------------------------------------------------
__global__ __launch_bounds__(256) void init_k(
    const float* __restrict__ Wq, const float* __restrict__ Wk,
    const float* __restrict__ Wv, const float* __restrict__ Wout,
    const float* __restrict__ Wtq, const float* __restrict__ Wtk,
    short* __restrict__ out, int* __restrict__ degcur, int n2) {
  int gid = blockIdx.x * 256 + threadIdx.x;
  if (gid < n2) degcur[gid] = 0;
  if (gid >= 9216) return;
  bfrag8 v;
  if (gid < 8192) {
    int which = gid >> 11;
    int chunk = gid & 2047;
    const float* W = (which == 0) ? Wq : (which == 1) ? Wk
                   : (which == 2) ? Wv : Wout;
    int c  = chunk & 15;
    int g  = (chunk >> 4) & 3;
    int kt = (chunk >> 6) & 3;
    int ct = chunk >> 8;
    int col = ct * 16 + c;
    int k0 = kt * 32 + g * 8;
    #pragma unroll
    for (int i = 0; i < 8; ++i) v[i] = f2bf(W[(size_t)(k0 + i) * HID + col]);
  } else {
    int chunk = gid - 8192;
    int c  = chunk & 15;
    int g  = (chunk >> 4) & 3;
    int ct = (chunk >> 6) & 7;
    int qk = chunk >> 9;
    const float* W = qk ? Wtk : Wtq;
    int col = ct * 16 + c;
    int k0 = g * 8;
    #pragma unroll
    for (int i = 0; i < 8; ++i) v[i] = f2bf(W[(size_t)(k0 + i) * HID + col]);
  }
  *(bfrag8*)(out + (size_t)gid * 8) = v;
}

// ---------------------------------------------------------------------------
// GEMM body, 512 threads (8 waves), swapped operands (A=W, B=X):
// lane (lr,g) owns output row row0+lr, cols ct*16+g*4..+3 -> dense stores.
// Bias staged in LDS and folded into the accumulator INIT (MFMA C-in), so no
// bias registers live across the chunk loop (memory-clobber pins the reads).
// MODE 0: Y[row*128+col]; MODE 1: QV Q-half; MODE 2: QV V-half.
// ---------------------------------------------------------------------------
template <typename IT, typename OT, int MODE>
__device__ __forceinline__ void gemm_body(
    short* __restrict__ Ws, float* __restrict__ bshf, const IT* __restrict__ X,
    const short* __restrict__ Wp, const float* __restrict__ b,
    OT* __restrict__ Y, int nrows, int bx0, int stride, int nchunks) {
  const int t = threadIdx.x;
  #pragma unroll
  for (int it = 0; it < 4; ++it) {
    int chunk = t + it * 512;
    *(bfrag8*)(&Ws[chunk * 8]) = *(const bfrag8*)(Wp + (size_t)chunk * 8);
  }
  if (t < 128) bshf[t] = b[t];
  __syncthreads();

  const int w  = t >> 6;   // 0..7
  const int l  = t & 63;
  const int lr = l & 15;
  const int g  = l >> 4;

  for (int ch = bx0; ch < nchunks; ch += stride) {
    asm volatile("" ::: "memory");  // keep bias/W LDS reads inside the loop
    const int row0 = ch * 128 + w * 16;
    const int arow = min(row0 + lr, nrows - 1);

    facc4 acc[8];
    #pragma unroll
    for (int ct = 0; ct < 8; ++ct)
      acc[ct] = *(const facc4*)(&bshf[ct * 16 + g * 4]);

    #pragma unroll
    for (int kt = 0; kt < 4; ++kt) {
      bfrag8 a;
      if constexpr (sizeof(IT) == 4) {
        const float* xp = (const float*)X + (size_t)arow * HID + kt * 32 + g * 8;
        float xv[8];
        *(facc4*)(xv)     = *(const facc4*)(xp);
        *(facc4*)(xv + 4) = *(const facc4*)(xp + 4);
        #pragma unroll
        for (int i = 0; i < 8; ++i) a[i] = f2bf(xv[i]);
      } else {
        a = *(const bfrag8*)((const short*)X + (size_t)arow * HID + kt * 32 + g * 8);
      }
      #pragma unroll
      for (int ct = 0; ct < 8; ++ct) {
        bfrag8 bf = *(const bfrag8*)(&Ws[(((ct * 4 + kt) * 4 + g) * 16 + lr) * 8]);
        acc[ct] = __builtin_amdgcn_mfma_f32_16x16x32_bf16(bf, a, acc[ct], 0, 0, 0);
      }
    }

    const int row = row0 + lr;
    if (row < nrows) {
      #pragma unroll
      for (int ct = 0; ct < 8; ++ct) {
        const int col0 = ct * 16 + g * 4;
        if constexpr (sizeof(OT) == 4) {
          *(facc4*)((float*)Y + (size_t)row * HID + col0) = acc[ct];
        } else {
          bf4 p;
          #pragma unroll
          for (int j = 0; j < 4; ++j) p[j] = f2bf(acc[ct][j]);
          size_t base;
          if constexpr (MODE == 0) base = (size_t)row * HID + col0;
          else base = (size_t)row * 256 + col0 + (MODE == 2 ? 128 : 0);
          *(bf4*)((short*)Y + base) = p;
        }
      }
    }
  }
}

// ---------------------------------------------------------------------------
// Temporal body, 512 threads: edges-on-COLUMNS MFMA (A=W, B=T^T). 128 edges
// per tile (16/wave). Sums parked in a padded per-wave LDS slab (stride 10),
// then one coalesced 8B/lane store per tile.
// ---------------------------------------------------------------------------
__device__ __forceinline__ void temporal_body(
    short* __restrict__ Ws, float* __restrict__ bsh, float* __restrict__ tsh,
    const float* __restrict__ T, const short* __restrict__ Wp,
    const float* __restrict__ btq, const float* __restrict__ btk,
    float* __restrict__ ts, int E, int ntiles, int bx, int nblk) {
  const int t = threadIdx.x;
  #pragma unroll
  for (int it = 0; it < 2; ++it) {
    int chunk = t + it * 512;
    *(bfrag8*)(&Ws[chunk * 8]) = *(const bfrag8*)(Wp + (size_t)chunk * 8);
  }
  if (t < 256) bsh[t] = (t < 128) ? btq[t] : btk[t - 128];
  __syncthreads();

  const int w = t >> 6;  // 0..7
  const int l = t & 63;
  const int c = l & 15;  // edge within 16-edge wave tile
  const int g = l >> 4;  // feature-row group
  float* mytsh = tsh + w * 160;  // [16 edges][10] padded

  for (int tile = bx; tile < ntiles; tile += nblk) {
    const int e0 = tile * 128 + w * 16;
    const int ar = min(e0 + c, E - 1);
    const float* tp = T + (size_t)ar * 32 + g * 8;
    float xv[8];
    *(facc4*)(xv)     = *(const facc4*)(tp);
    *(facc4*)(xv + 4) = *(const facc4*)(tp + 4);
    bfrag8 tb;
    #pragma unroll
    for (int i = 0; i < 8; ++i) tb[i] = f2bf(xv[i]);

    #pragma unroll 1
    for (int ct = 0; ct < 8; ++ct) {
      facc4 accq = *(const facc4*)(&bsh[ct * 16 + g * 4]);
      bfrag8 wq = *(const bfrag8*)(&Ws[(ct * 64 + g * 16 + c) * 8]);
      accq = __builtin_amdgcn_mfma_f32_16x16x32_bf16(wq, tb, accq, 0, 0, 0);
      facc4 acck = *(const facc4*)(&bsh[128 + ct * 16 + g * 4]);
      bfrag8 wk = *(const bfrag8*)(&Ws[(512 + ct * 64 + g * 16 + c) * 8]);
      acck = __builtin_amdgcn_mfma_f32_16x16x32_bf16(wk, tb, acck, 0, 0, 0);

      float s = accq[0] * acck[0] + accq[1] * acck[1] +
                accq[2] * acck[2] + accq[3] * acck[3];
      s += __shfl_xor(s, 16, 64);
      s += __shfl_xor(s, 32, 64);
      if (g == 0) mytsh[c * 10 + ct] = s;
    }
    int e = e0 + (l >> 2);
    if (e < E) {
      float2 v2 = *(const float2*)(&mytsh[(l >> 2) * 10 + (l & 3) * 2]);
      *(float2*)(ts + (size_t)e0 * 8 + l * 2) = v2;
    }
  }
}

// ---------------------------------------------------------------------------
// Mega kernel (512 threads): QKV projections + temporal + degree count.
// ---------------------------------------------------------------------------
__global__ __launch_bounds__(512, 6) void mega_k(
    const float* __restrict__ query, const float* __restrict__ key,
    const float* __restrict__ value, const float* __restrict__ temporal,
    const short* __restrict__ Wpre,
    const float* __restrict__ bq, const float* __restrict__ bk,
    const float* __restrict__ bv, const float* __restrict__ btq,
    const float* __restrict__ btk,
    short* __restrict__ QVp, short* __restrict__ Kp,
    float* __restrict__ tscores, const int* __restrict__ tgt,
    int* __restrict__ deg, int N, int E, int gq, int nch, int ntiles) {
  __shared__ __align__(16) char smem[33280];  // 32KB Ws + 512B bias (GEMM)
  short* Ws = (short*)smem;
  float* baux = (float*)(smem + 32768);
  const int bx = blockIdx.x;
  if (bx < gq) {
    gemm_body<float, short, 1>(Ws, baux, query, Wpre + 0 * 16384, bq, QVp,
                               N, bx, gq, nch);
  } else if (bx < 2 * gq) {
    gemm_body<float, short, 0>(Ws, baux, key, Wpre + 1 * 16384, bk, Kp,
                               N, bx - gq, gq, nch);
  } else if (bx < 3 * gq) {
    gemm_body<float, short, 2>(Ws, baux, value, Wpre + 2 * 16384, bv, QVp,
                               N, bx - 2 * gq, gq, nch);
  } else if (bx < 3 * gq + TBLK) {
    // temporal: Ws 16KB | bsh 1KB @16384 | slab 5KB @17408
    temporal_body(Ws, (float*)(smem + 16384), (float*)(smem + 17408),
                  temporal, Wpre + 4 * 16384, btq, btk, tscores, E, ntiles,
                  bx - 3 * gq, TBLK);
  } else {
    int gid = (bx - 3 * gq - TBLK) * 512 + threadIdx.x;
    if (gid < E) atomicAdd(&deg[tgt[gid]], 1);
  }
}

// standalone GEMM for the output projection (512 threads)
template <typename IT, typename OT, int MODE>
__global__ __launch_bounds__(512, 6) void gemm_mfma_k(
    const IT* __restrict__ X, const short* __restrict__ Wp,
    const float* __restrict__ b, OT* __restrict__ Y, int nrows,
    int stride, int nchunks) {
  __shared__ __align__(16) char smem[33280];
  gemm_body<IT, OT, MODE>((short*)smem, (float*)(smem + 32768), X, Wp, b, Y,
                          nrows, blockIdx.x, stride, nchunks);
}

// ---------------------------------------------------------------------------
// CSR scan + scatter
// ---------------------------------------------------------------------------
__global__ __launch_bounds__(256) void block_sum_k(const int* __restrict__ deg,
                                                   int* __restrict__ bsum, int n) {
  __shared__ int sd[256];
  const int base = blockIdx.x * 1024;
  const int t = threadIdx.x;
  int s = 0;
  #pragma unroll
  for (int j = 0; j < 4; ++j) {
    int i = base + t + j * 256;
    if (i < n) s += deg[i];
  }
  sd[t] = s;
  __syncthreads();
  for (int st = 128; st; st >>= 1) {
    if (t < st) sd[t] += sd[t + st];
    __syncthreads();
  }
  if (t == 0) bsum[blockIdx.x] = sd[0];
}

__global__ __launch_bounds__(1024) void scan_partials_k(const int* __restrict__ bsum,
                                                        int* __restrict__ boff, int G) {
  __shared__ int sd[1024];
  const int t = threadIdx.x;
  int v = (t < G) ? bsum[t] : 0;
  sd[t] = v;
  __syncthreads();
  for (int s = 1; s < 1024; s <<= 1) {
    int a = (t >= s) ? sd[t - s] : 0;
    __syncthreads();
    sd[t] += a;
    __syncthreads();
  }
  if (t < G) boff[t] = sd[t] - v;
}

__global__ __launch_bounds__(256) void block_scan_k(const int* __restrict__ deg,
                                                    const int* __restrict__ boff,
                                                    int* __restrict__ off, int n) {
  __shared__ int sd[256];
  const int base = blockIdx.x * 1024;
  const int t = threadIdx.x;
  const int i0 = base + t * 4;
  int v[4];
  int s = 0;
  #pragma unroll
  for (int j = 0; j < 4; ++j) {
    v[j] = (i0 + j < n) ? deg[i0 + j] : 0;
    s += v[j];
  }
  const int own = s;
  sd[t] = s;
  __syncthreads();
  for (int st = 1; st < 256; st <<= 1) {
    int a = (t >= st) ? sd[t - st] : 0;
    __syncthreads();
    sd[t] += a;
    __syncthreads();
  }
  int acc = boff[blockIdx.x] + sd[t] - own;
  #pragma unroll
  for (int j = 0; j < 4; ++j) {
    int idx = i0 + j;
    if (idx < n) {
      off[idx] = acc;
      acc += v[j];
      if (idx == n - 1) off[n] = acc;
    }
  }
}

// writes (edge id, src id) pairs so the softmax kernel never gathers src[]
__global__ __launch_bounds__(256) void scatter_k(const int* __restrict__ src,
                                                 const int* __restrict__ tgt,
                                                 const int* __restrict__ off,
                                                 int* __restrict__ cur,
                                                 int2* __restrict__ elist2, int E) {
  int gid = blockIdx.x * 256 + threadIdx.x;
  if (gid < E) {
    int n = tgt[gid];
    int p = atomicAdd(&cur[n], 1);
    elist2[off[n] + p] = make_int2(gid, src[gid]);
  }
}

// ---------------------------------------------------------------------------
// Per-node QK score + softmax + aggregation, ONE gather pass, no max-tracking
// (scores bounded ~|30| << 88; softmax is shift-invariant).
// QV rows [Q128|V128]: lane g reads 8B q at +g*4 and 8B v at +128+g*4.
// 32 lanes per node, 8 nodes per 256-thread block, no __syncthreads.
// ---------------------------------------------------------------------------
__global__ __launch_bounds__(256) void softmax_agg_k(
    const float* __restrict__ tscores, const short* __restrict__ QVp,
    const short* __restrict__ Kp, const int* __restrict__ off,
    const int2* __restrict__ elist2, float* __restrict__ attn_w,
    short* __restrict__ aggb, int N) {
  __shared__ int esh[8][MAXD];
  __shared__ int ssh[8][MAXD];
  __shared__ float sraw[8][MAXD][8];  // unnormalized exp weights per head
  const int t = threadIdx.x;
  const int grp = t >> 5;
  const int g = t & 31;
  const int h = g >> 2;
  const int j = g & 3;
  const int n = blockIdx.x * 8 + grp;
  if (n >= N) return;

  const int s0 = off[n];
  const int deg = off[n + 1] - s0;

  float kr[4];
  {
    bf4 k4 = *(const bf4*)(Kp + (size_t)n * HID + g * 4);
    #pragma unroll
    for (int q = 0; q < 4; ++q) kr[q] = bf2f(k4[q]);
  }

  if (deg <= MAXD) {
    for (int i = g; i < deg; i += 32) {
      int2 es = elist2[s0 + i];
      esh[grp][i] = es.x;
      ssh[grp][i] = es.y;
    }

    float lsum = 0.f;
    float a0 = 0.f, a1 = 0.f, a2 = 0.f, a3 = 0.f;
    int i = 0;
    for (; i + 4 <= deg; i += 4) {
      const size_t b0 = (size_t)ssh[grp][i]     * 256 + g * 4;
      const size_t b1 = (size_t)ssh[grp][i + 1] * 256 + g * 4;
      const size_t b2 = (size_t)ssh[grp][i + 2] * 256 + g * 4;
      const size_t b3 = (size_t)ssh[grp][i + 3] * 256 + g * 4;
      bf4 q0 = *(const bf4*)(QVp + b0);
      bf4 q1 = *(const bf4*)(QVp + b1);
      bf4 q2 = *(const bf4*)(QVp + b2);
      bf4 q3 = *(const bf4*)(QVp + b3);
      bf4 v0 = *(const bf4*)(QVp + b0 + 128);
      bf4 v1 = *(const bf4*)(QVp + b1 + 128);
      bf4 v2 = *(const bf4*)(QVp + b2 + 128);
      bf4 v3 = *(const bf4*)(QVp + b3 + 128);
      float ts0 = tscores[(size_t)esh[grp][i]     * 8 + h];
      float ts1 = tscores[(size_t)esh[grp][i + 1] * 8 + h];
      float ts2 = tscores[(size_t)esh[grp][i + 2] * 8 + h];
      float ts3 = tscores[(size_t)esh[grp][i + 3] * 8 + h];
      float p0 = bf2f(q0[0]) * kr[0] + bf2f(q0[1]) * kr[1] +
                 bf2f(q0[2]) * kr[2] + bf2f(q0[3]) * kr[3];
      float p1 = bf2f(q1[0]) * kr[0] + bf2f(q1[1]) * kr[1] +
                 bf2f(q1[2]) * kr[2] + bf2f(q1[3]) * kr[3];
      float p2 = bf2f(q2[0]) * kr[0] + bf2f(q2[1]) * kr[1] +
                 bf2f(q2[2]) * kr[2] + bf2f(q2[3]) * kr[3];
      float p3 = bf2f(q3[0]) * kr[0] + bf2f(q3[1]) * kr[1] +
                 bf2f(q3[2]) * kr[2] + bf2f(q3[3]) * kr[3];
      p0 += __shfl_xor(p0, 1, 4); p0 += __shfl_xor(p0, 2, 4);
      p1 += __shfl_xor(p1, 1, 4); p1 += __shfl_xor(p1, 2, 4);
      p2 += __shfl_xor(p2, 1, 4); p2 += __shfl_xor(p2, 2, 4);
      p3 += __shfl_xor(p3, 1, 4); p3 += __shfl_xor(p3, 2, 4);
      float w0 = __expf(ts0 + p0 * 0.25f);
      float w1 = __expf(ts1 + p1 * 0.25f);
      float w2 = __expf(ts2 + p2 * 0.25f);
      float w3 = __expf(ts3 + p3 * 0.25f);
      if (j == 0) {
        sraw[grp][i][h]     = w0;
        sraw[grp][i + 1][h] = w1;
        sraw[grp][i + 2][h] = w2;
        sraw[grp][i + 3][h] = w3;
      }
      lsum += (w0 + w1) + (w2 + w3);
      a0 += w0 * bf2f(v0[0]) + w1 * bf2f(v1[0]) +
            w2 * bf2f(v2[0]) + w3 * bf2f(v3[0]);
      a1 += w0 * bf2f(v0[1]) + w1 * bf2f(v1[1]) +
            w2 * bf2f(v2[1]) + w3 * bf2f(v3[1]);
      a2 += w0 * bf2f(v0[2]) + w1 * bf2f(v1[2]) +
            w2 * bf2f(v2[2]) + w3 * bf2f(v3[2]);
      a3 += w0 * bf2f(v0[3]) + w1 * bf2f(v1[3]) +
            w2 * bf2f(v2[3]) + w3 * bf2f(v3[3]);
    }
    for (; i < deg; ++i) {
      const size_t b0 = (size_t)ssh[grp][i] * 256 + g * 4;
      bf4 q0 = *(const bf4*)(QVp + b0);
      bf4 v0 = *(const bf4*)(QVp + b0 + 128);
      float ts0 = tscores[(size_t)esh[grp][i] * 8 + h];
      float p0 = bf2f(q0[0]) * kr[0] + bf2f(q0[1]) * kr[1] +
                 bf2f(q0[2]) * kr[2] + bf2f(q0[3]) * kr[3];
      p0 += __shfl_xor(p0, 1, 4); p0 += __shfl_xor(p0, 2, 4);
      float w0 = __expf(ts0 + p0 * 0.25f);
      if (j == 0) sraw[grp][i][h] = w0;
      lsum += w0;
      a0 += w0 * bf2f(v0[0]);
      a1 += w0 * bf2f(v0[1]);
      a2 += w0 * bf2f(v0[2]);
      a3 += w0 * bf2f(v0[3]);
    }
    float invl = (lsum > 0.f) ? 1.0f / lsum : 0.f;

    bf4 st;
    st[0] = f2bf(a0 * invl); st[1] = f2bf(a1 * invl);
    st[2] = f2bf(a2 * invl); st[3] = f2bf(a3 * invl);
    *(bf4*)(aggb + (size_t)n * HID + g * 4) = st;

    if (j == 0) {
      for (int q = 0; q < deg; ++q)
        attn_w[(size_t)esh[grp][q] * 8 + h] = sraw[grp][q][h] * invl;
    }
  } else {
    // fallback (deg > MAXD): 3-pass unstaged, max-subtracted
    float m = -3.0e38f;
    for (int q = 0; q < deg; ++q) {
      int2 es = elist2[s0 + q];
      bf4 q4 = *(const bf4*)(QVp + (size_t)es.y * 256 + g * 4);
      float p = bf2f(q4[0]) * kr[0] + bf2f(q4[1]) * kr[1] +
                bf2f(q4[2]) * kr[2] + bf2f(q4[3]) * kr[3];
      p += __shfl_xor(p, 1, 4); p += __shfl_xor(p, 2, 4);
      m = fmaxf(m, tscores[(size_t)es.x * 8 + h] + p * 0.25f);
    }
    float l = 0.f;
    for (int q = 0; q < deg; ++q) {
      int2 es = elist2[s0 + q];
      bf4 q4 = *(const bf4*)(QVp + (size_t)es.y * 256 + g * 4);
      float p = bf2f(q4[0]) * kr[0] + bf2f(q4[1]) * kr[1] +
                bf2f(q4[2]) * kr[2] + bf2f(q4[3]) * kr[3];
      p += __shfl_xor(p, 1, 4); p += __shfl_xor(p, 2, 4);
      l += __expf(tscores[(size_t)es.x * 8 + h] + p * 0.25f - m);
    }
    float invl = (l > 0.f) ? 1.0f / l : 0.f;
    float a0 = 0.f, a1 = 0.f, a2 = 0.f, a3 = 0.f;
    for (int q = 0; q < deg; ++q) {
      int2 es = elist2[s0 + q];
      bf4 q4 = *(const bf4*)(QVp + (size_t)es.y * 256 + g * 4);
      bf4 v4 = *(const bf4*)(QVp + (size_t)es.y * 256 + 128 + g * 4);
      float p = bf2f(q4[0]) * kr[0] + bf2f(q4[1]) * kr[1] +
                bf2f(q4[2]) * kr[2] + bf2f(q4[3]) * kr[3];
      p += __shfl_xor(p, 1, 4); p += __shfl_xor(p, 2, 4);
      float w = __expf(tscores[(size_t)es.x * 8 + h] + p * 0.25f - m) * invl;
      a0 += w * bf2f(v4[0]);
      a1 += w * bf2f(v4[1]);
      a2 += w * bf2f(v4[2]);
      a3 += w * bf2f(v4[3]);
      if (j == 0) attn_w[(size_t)es.x * 8 + h] = w;
    }
    bf4 st;
    st[0] = f2bf(a0); st[1] = f2bf(a1); st[2] = f2bf(a2); st[3] = f2bf(a3);
    *(bf4*)(aggb + (size_t)n * HID + g * 4) = st;
  }
}

// ---------------------------------------------------------------------------
extern "C" void kernel_launch(void* const* d_in, const int* in_sizes, int n_in,
                              void* d_out, int out_size, void* d_ws, size_t ws_size,
                              hipStream_t stream) {
  const float* query    = (const float*)d_in[0];
  const float* key      = (const float*)d_in[1];
  const float* value    = (const float*)d_in[2];
  const float* temporal = (const float*)d_in[3];
  const int*   eidx     = (const int*)d_in[4];
  const float* Wq   = (const float*)d_in[5];
  const float* bq   = (const float*)d_in[6];
  const float* Wk   = (const float*)d_in[7];
  const float* bk   = (const float*)d_in[8];
  const float* Wv   = (const float*)d_in[9];
  const float* bv   = (const float*)d_in[10];
  const float* Wtq  = (const float*)d_in[11];
  const float* btq  = (const float*)d_in[12];
  const float* Wtk  = (const float*)d_in[13];
  const float* btk  = (const float*)d_in[14];
  const float* Wout = (const float*)d_in[15];
  const float* bout = (const float*)d_in[16];

  const int N = in_sizes[0] / HID;
  const int E = in_sizes[4] / 2;
  const int* src = eidx;
  const int* tgt = eidx + E;

  char* ws = (char*)d_ws;
  short* QVp = (short*)ws;                     ws += (size_t)N * 256 * 2;
  short* Kp = (short*)ws;                      ws += (size_t)N * HID * 2;
  short* aggb = (short*)ws;                    ws += (size_t)N * HID * 2;
  float* tscores = (float*)ws;                 ws += (size_t)E * 8 * 4;
  int* deg   = (int*)ws;                       ws += (size_t)N * 4;
  int* cur   = (int*)ws;                       ws += (size_t)N * 4;
  int* off   = (int*)ws;                       ws += (size_t)(N + 2) * 4;  // pad->8B align
  int2* elist2 = (int2*)ws;                    ws += (size_t)E * 8;
  int* bsum  = (int*)ws;                       ws += 1024 * 4;
  int* boff  = (int*)ws;                       ws += 1024 * 4;
  short* Wpre = (short*)ws;                    // 9216 * 16B

  const int G = (N + 1023) / 1024;
  const int nch = (N + 127) / 128;           // GEMM chunks of 128 rows
  const int gq = (nch + CH - 1) / CH;        // blocks per GEMM section
  const int ntiles = (E + 127) / 128;        // temporal tiles of 128 edges
  const int cblk = (E + 511) / 512;          // count blocks (512 thr)

  dim3 b256(256), b512(512);
  init_k<<<(2 * N + 255) / 256, b256, 0, stream>>>(Wq, Wk, Wv, Wout, Wtq, Wtk,
                                                   Wpre, deg, 2 * N);
  mega_k<<<3 * gq + TBLK + cblk, b512, 0, stream>>>(
      query, key, value, temporal, Wpre, bq, bk, bv, btq, btk,
      QVp, Kp, tscores, tgt, deg, N, E, gq, nch, ntiles);

  block_sum_k<<<G, b256, 0, stream>>>(deg, bsum, N);
  scan_partials_k<<<1, 1024, 0, stream>>>(bsum, boff, G);
  block_scan_k<<<G, b256, 0, stream>>>(deg, boff, off, N);
  scatter_k<<<(E + 255) / 256, b256, 0, stream>>>(src, tgt, off, cur, elist2, E);

  float* attn_w = (float*)d_out + (size_t)N * HID;
  softmax_agg_k<<<(N + 7) / 8, b256, 0, stream>>>(tscores, QVp, Kp, off,
                                                  elist2, attn_w, aggb, N);

  gemm_mfma_k<short, float, 0><<<gq, b512, 0, stream>>>(aggb, Wpre + 3 * 16384,
                                                        bout, (float*)d_out, N,
                                                        gq, nch);
}